// Round 1
// baseline (316.923 us; speedup 1.0000x reference)
//
#include <hip/hip_runtime.h>

typedef __attribute__((ext_vector_type(8))) short bf16x8;
typedef __attribute__((ext_vector_type(4))) float f32x4;

#define MFMA(a,b,c) __builtin_amdgcn_mfma_f32_16x16x32_bf16(a,b,c,0,0,0)
#define NEG_INF (-__builtin_inff())

__device__ __forceinline__ unsigned short f2b(float f) {
  unsigned int u = __float_as_uint(f);
  u = u + 0x7fffu + ((u >> 16) & 1u);
  return (unsigned short)(u >> 16);
}

__device__ __forceinline__ void gload_lds16(const unsigned short* g, unsigned short* l) {
  __builtin_amdgcn_global_load_lds((const __attribute__((address_space(1))) void*)g,
                                   (__attribute__((address_space(3))) void*)l, 16, 0, 0);
}

// ---------------- fp32 -> bf16 conversion (vectorized x4) ----------------
__global__ void cvt_bf16(const float* __restrict__ in, unsigned short* __restrict__ out, int n4) {
  int i = blockIdx.x * blockDim.x + threadIdx.x;
  if (i < n4) {
    float4 v = reinterpret_cast<const float4*>(in)[i];
    ushort4 o;
    o.x = f2b(v.x); o.y = f2b(v.y); o.z = f2b(v.z); o.w = f2b(v.w);
    reinterpret_cast<ushort4*>(out)[i] = o;
  }
}

// ---------------- GEMM: C[M][N] = A[M][K] @ B[N][K]^T (+bias) ----------------
// m97 structure: 128x128 tile, BK=32, 4 waves (2x2), each wave 64x64 (4x4 frags)
template<int OUT_BF16>
__global__ __launch_bounds__(256) void gemm_bt(
    const unsigned short* __restrict__ A,
    const unsigned short* __restrict__ Bw,
    unsigned short* __restrict__ Cb,
    float* __restrict__ Cf,
    const float* __restrict__ bias,
    int M, int N, int K)
{
  __shared__ unsigned short As[128*32];
  __shared__ unsigned short Bs[128*32];
  const int tid  = threadIdx.x;
  const int w    = tid >> 6, lane = tid & 63;
  const int wr   = w >> 1,   wc   = w & 1;
  const int g    = lane >> 4, li  = lane & 15;
  const int m0   = blockIdx.x * 128, n0 = blockIdx.y * 128;

  f32x4 acc[4][4] = {};

  // staging geometry: LDS elem e = (w*2+L)*512 + lane*8 ; row=e/32, col=e%32
  const int rS0 = (w*2+0)*16 + (lane>>2);
  const int rS1 = (w*2+1)*16 + (lane>>2);
  const int cS  = (lane&3)*8;
  const unsigned short* gA0 = A  + (size_t)(m0+rS0)*K + cS;
  const unsigned short* gA1 = A  + (size_t)(m0+rS1)*K + cS;
  const unsigned short* gB0 = Bw + (size_t)(n0+rS0)*K + cS;
  const unsigned short* gB1 = Bw + (size_t)(n0+rS1)*K + cS;
  unsigned short* lA0 = &As[(w*2+0)*512];
  unsigned short* lA1 = &As[(w*2+1)*512];
  unsigned short* lB0 = &Bs[(w*2+0)*512];
  unsigned short* lB1 = &Bs[(w*2+1)*512];

  for (int k0 = 0; k0 < K; k0 += 32) {
    gload_lds16(gA0 + k0, lA0);
    gload_lds16(gA1 + k0, lA1);
    gload_lds16(gB0 + k0, lB0);
    gload_lds16(gB1 + k0, lB1);
    __syncthreads();

    bf16x8 af[4], bf[4];
    #pragma unroll
    for (int i = 0; i < 4; ++i)
      af[i] = *(const bf16x8*)(&As[(wr*64 + i*16 + li)*32 + g*8]);
    #pragma unroll
    for (int j = 0; j < 4; ++j)
      bf[j] = *(const bf16x8*)(&Bs[(wc*64 + j*16 + li)*32 + g*8]);
    #pragma unroll
    for (int i = 0; i < 4; ++i)
      #pragma unroll
      for (int j = 0; j < 4; ++j)
        acc[i][j] = MFMA(af[i], bf[j], acc[i][j]);
    __syncthreads();
  }

  // epilogue: C row = g*4+r (+frag), col = li (+frag)
  #pragma unroll
  for (int i = 0; i < 4; ++i) {
    #pragma unroll
    for (int j = 0; j < 4; ++j) {
      int col = n0 + wc*64 + j*16 + li;
      #pragma unroll
      for (int r = 0; r < 4; ++r) {
        int row = m0 + wr*64 + i*16 + g*4 + r;
        float v = acc[i][j][r];
        if (OUT_BF16) {
          Cb[(size_t)row*N + col] = f2b(v);
        } else {
          Cf[(size_t)row*N + col] = v + bias[col];
        }
      }
    }
  }
}

// ---------------- Flash attention ----------------
// grid: (S/64, B*H); 4 waves, wave w owns q rows [q0+w*16, q0+w*16+15]
// QK^T: C[q][kv] (A=Q frag, B=K rows);  PV: O^T[d][q] (A=Vt rows, B=P rows)
__global__ __launch_bounds__(256) void attn_kernel(
    const unsigned short* __restrict__ Qb,
    const unsigned short* __restrict__ Kb,
    const unsigned short* __restrict__ Vb,
    const unsigned char*  __restrict__ amask,
    const int* __restrict__ causal_p,
    unsigned short* __restrict__ Ob,
    int B, int H, int S)
{
  const int D = H * 64;
  __shared__ unsigned short Ks [64*80];   // [kv][dk] padded
  __shared__ unsigned short Vts[64*80];   // [dk][kv] padded (transposed V)
  __shared__ unsigned short Ps [4][16*80];// per-wave P [q][kv] padded

  const int tid = threadIdx.x, w = tid >> 6, lane = tid & 63;
  const int g = lane >> 4, li = lane & 15;
  const int qt = blockIdx.x, bh = blockIdx.y;
  const int b = bh / H, h = bh % H;
  const int q0 = qt * 64;
  const int causal = causal_p[0];

  // Q fragments (held for the whole kernel)
  const int qrow = q0 + w*16 + li;
  const unsigned short* qp = Qb + (size_t)(b*S + qrow)*D + h*64 + g*8;
  const bf16x8 qf0 = *(const bf16x8*)(qp);
  const bf16x8 qf1 = *(const bf16x8*)(qp + 32);

  f32x4 oacc[4] = {};
  float m_own[4] = {NEG_INF, NEG_INF, NEG_INF, NEG_INF};
  float l_own[4] = {0.f, 0.f, 0.f, 0.f};

  const int ntile = causal ? (qt + 1) : (S >> 6);
  for (int t = 0; t < ntile; ++t) {
    const int kv0 = t * 64;
    __syncthreads();  // previous tile's LDS reads done
    // stage K rows and transposed V
    for (int c = tid; c < 512; c += 256) {
      int row = c >> 3, col8 = c & 7;
      const size_t goff = (size_t)(b*S + kv0 + row)*D + h*64 + col8*8;
      bf16x8 kvv = *(const bf16x8*)(Kb + goff);
      *(bf16x8*)(&Ks[row*80 + col8*8]) = kvv;
      bf16x8 vv = *(const bf16x8*)(Vb + goff);
      #pragma unroll
      for (int j = 0; j < 8; ++j)
        Vts[(col8*8 + j)*80 + row] = (unsigned short)vv[j];
    }
    __syncthreads();

    // QK^T -> sa[ni] : C[q=g*4+r][kv=ni*16+li]
    f32x4 sa[4] = {};
    #pragma unroll
    for (int ni = 0; ni < 4; ++ni) {
      bf16x8 kf0 = *(const bf16x8*)(&Ks[(ni*16 + li)*80 + g*8]);
      bf16x8 kf1 = *(const bf16x8*)(&Ks[(ni*16 + li)*80 + 32 + g*8]);
      sa[ni] = MFMA(qf0, kf0, sa[ni]);
      sa[ni] = MFMA(qf1, kf1, sa[ni]);
    }

    // scale + causal + mask
    float pv[4][4]; // [ni][r]
    #pragma unroll
    for (int ni = 0; ni < 4; ++ni) {
      int kvg = kv0 + ni*16 + li;
      #pragma unroll
      for (int r = 0; r < 4; ++r) {
        int qg = q0 + w*16 + g*4 + r;
        float s = sa[ni][r] * 0.125f;
        bool dead = (causal && (kvg > qg)) ||
                    (amask[(size_t)(b*S + qg)*S + kvg] != 0);
        pv[ni][r] = dead ? NEG_INF : s;
      }
    }

    // online softmax per row r (rows g*4+r, replicated across 16 lanes)
    float corr[4];
    #pragma unroll
    for (int r = 0; r < 4; ++r) {
      float mx = fmaxf(fmaxf(pv[0][r], pv[1][r]), fmaxf(pv[2][r], pv[3][r]));
      mx = fmaxf(mx, __shfl_xor(mx, 1, 16));
      mx = fmaxf(mx, __shfl_xor(mx, 2, 16));
      mx = fmaxf(mx, __shfl_xor(mx, 4, 16));
      mx = fmaxf(mx, __shfl_xor(mx, 8, 16));
      float mn = fmaxf(m_own[r], mx);
      corr[r] = (m_own[r] == NEG_INF) ? 0.f : __expf(m_own[r] - mn);
      float rs = 0.f;
      #pragma unroll
      for (int ni = 0; ni < 4; ++ni) {
        float p = (mn == NEG_INF) ? 0.f : __expf(pv[ni][r] - mn);
        pv[ni][r] = p;
        rs += p;
      }
      rs += __shfl_xor(rs, 1, 16);
      rs += __shfl_xor(rs, 2, 16);
      rs += __shfl_xor(rs, 4, 16);
      rs += __shfl_xor(rs, 8, 16);
      l_own[r] = l_own[r] * corr[r] + rs;
      m_own[r] = mn;
    }

    // write P (bf16) to per-wave LDS [q][kv]
    #pragma unroll
    for (int ni = 0; ni < 4; ++ni)
      #pragma unroll
      for (int r = 0; r < 4; ++r)
        Ps[w][(g*4 + r)*80 + ni*16 + li] = f2b(pv[ni][r]);

    // redistribute correction to q=li layout: lane 16*(li>>2)+(li&3) publishes corr[li&3]
    float pubc = (lane&3)==0 ? corr[0] : (lane&3)==1 ? corr[1] : (lane&3)==2 ? corr[2] : corr[3];
    float corr_q = __shfl(pubc, ((li >> 2) << 4) + (li & 3), 64);

    #pragma unroll
    for (int di = 0; di < 4; ++di) {
      oacc[di][0] *= corr_q; oacc[di][1] *= corr_q;
      oacc[di][2] *= corr_q; oacc[di][3] *= corr_q;
    }

    // PV: O^T[d][q] += Vt[d][kv] * P[q][kv]
    #pragma unroll
    for (int c = 0; c < 2; ++c) {
      bf16x8 pf = *(const bf16x8*)(&Ps[w][li*80 + c*32 + g*8]);
      #pragma unroll
      for (int di = 0; di < 4; ++di) {
        bf16x8 vf = *(const bf16x8*)(&Vts[(di*16 + li)*80 + c*32 + g*8]);
        oacc[di] = MFMA(vf, pf, oacc[di]);
      }
    }
  }

  // epilogue: divide by l (q = li), write O[b, q, h*64 + d] bf16
  float publ = (lane&3)==0 ? l_own[0] : (lane&3)==1 ? l_own[1] : (lane&3)==2 ? l_own[2] : l_own[3];
  float l_q = __shfl(publ, ((li >> 2) << 4) + (li & 3), 64);
  float rl = (l_q > 0.f) ? 1.0f / l_q : 0.f;
  #pragma unroll
  for (int di = 0; di < 4; ++di)
    #pragma unroll
    for (int r = 0; r < 4; ++r) {
      int d = di*16 + g*4 + r;
      Ob[(size_t)(b*S + q0 + w*16 + li)*D + h*64 + d] = f2b(oacc[di][r] * rl);
    }
}

extern "C" void kernel_launch(void* const* d_in, const int* in_sizes, int n_in,
                              void* d_out, int out_size, void* d_ws, size_t ws_size,
                              hipStream_t stream) {
  const float* query = (const float*)d_in[0];
  const float* key_  = (const float*)d_in[1];
  const float* value = (const float*)d_in[2];
  const unsigned char* amask = (const unsigned char*)d_in[3];
  const float* Wq   = (const float*)d_in[4];
  const float* Wk   = (const float*)d_in[5];
  const float* Wv   = (const float*)d_in[6];
  const float* Wout = (const float*)d_in[7];
  const float* b_out = (const float*)d_in[8];
  const int* is_causal = (const int*)d_in[9];
  float* out = (float*)d_out;

  const int B = 2, S = 2048, D = 1024, H = 16;
  const int M = B * S;                 // 4096
  const size_t nx = (size_t)M * D;     // 4,194,304
  const size_t nw = (size_t)D * D;     // 1,048,576

  unsigned short* ws = (unsigned short*)d_ws;
  unsigned short* xq = ws;
  unsigned short* xk = xq + nx;
  unsigned short* xv = xk + nx;
  unsigned short* wq = xv + nx;
  unsigned short* wk = wq + nw;
  unsigned short* wv = wk + nw;
  unsigned short* wo = wv + nw;
  unsigned short* qb = wo + nw;
  unsigned short* kb = qb + nx;
  unsigned short* vb = kb + nx;
  unsigned short* ob = xq;             // reuse: xq dead after Q-projection

  const int thr = 256;
  cvt_bf16<<<dim3((unsigned)((nx/4 + thr-1)/thr)), thr, 0, stream>>>(query, xq, (int)(nx/4));
  cvt_bf16<<<dim3((unsigned)((nx/4 + thr-1)/thr)), thr, 0, stream>>>(key_,  xk, (int)(nx/4));
  cvt_bf16<<<dim3((unsigned)((nx/4 + thr-1)/thr)), thr, 0, stream>>>(value, xv, (int)(nx/4));
  cvt_bf16<<<dim3((unsigned)((nw/4 + thr-1)/thr)), thr, 0, stream>>>(Wq,   wq, (int)(nw/4));
  cvt_bf16<<<dim3((unsigned)((nw/4 + thr-1)/thr)), thr, 0, stream>>>(Wk,   wk, (int)(nw/4));
  cvt_bf16<<<dim3((unsigned)((nw/4 + thr-1)/thr)), thr, 0, stream>>>(Wv,   wv, (int)(nw/4));
  cvt_bf16<<<dim3((unsigned)((nw/4 + thr-1)/thr)), thr, 0, stream>>>(Wout, wo, (int)(nw/4));

  dim3 gg(M/128, D/128);
  gemm_bt<1><<<gg, 256, 0, stream>>>(xq, wq, qb, nullptr, nullptr, M, D, D);
  gemm_bt<1><<<gg, 256, 0, stream>>>(xk, wk, kb, nullptr, nullptr, M, D, D);
  gemm_bt<1><<<gg, 256, 0, stream>>>(xv, wv, vb, nullptr, nullptr, M, D, D);

  attn_kernel<<<dim3(S/64, B*H), 256, 0, stream>>>(qb, kb, vb, amask, is_causal, ob, B, H, S);

  gemm_bt<0><<<gg, 256, 0, stream>>>(ob, wo, nullptr, out, b_out, M, D, D);
}

// Round 2
// 262.425 us; speedup vs baseline: 1.2077x; 1.2077x over previous
//
#include <hip/hip_runtime.h>

typedef __attribute__((ext_vector_type(8))) short bf16x8;
typedef __attribute__((ext_vector_type(4))) float f32x4;
typedef unsigned long long u64;

#define MFMA(a,b,c) __builtin_amdgcn_mfma_f32_16x16x32_bf16(a,b,c,0,0,0)
#define NEG_INF (-__builtin_inff())

__device__ __forceinline__ unsigned short f2b(float f) {
  unsigned int u = __float_as_uint(f);
  u = u + 0x7fffu + ((u >> 16) & 1u);
  return (unsigned short)(u >> 16);
}

__device__ __forceinline__ void gload_lds16(const unsigned short* g, unsigned short* l) {
  __builtin_amdgcn_global_load_lds((const __attribute__((address_space(1))) void*)g,
                                   (__attribute__((address_space(3))) void*)l, 16, 0, 0);
}

// ---------------- fused fp32 -> bf16 conversion for all 7 tensors ----------------
__global__ void cvt7(const float* s0, const float* s1, const float* s2,
                     const float* s3, const float* s4, const float* s5, const float* s6,
                     unsigned short* d0, unsigned short* d1, unsigned short* d2,
                     unsigned short* d3, unsigned short* d4, unsigned short* d5, unsigned short* d6,
                     int nbig, int nsmall) {
  const float* s; unsigned short* d; int n4;
  switch (blockIdx.y) {
    case 0: s=s0; d=d0; n4=nbig; break;
    case 1: s=s1; d=d1; n4=nbig; break;
    case 2: s=s2; d=d2; n4=nbig; break;
    case 3: s=s3; d=d3; n4=nsmall; break;
    case 4: s=s4; d=d4; n4=nsmall; break;
    case 5: s=s5; d=d5; n4=nsmall; break;
    default: s=s6; d=d6; n4=nsmall; break;
  }
  int i = blockIdx.x * blockDim.x + threadIdx.x;
  if (i < n4) {
    float4 v = reinterpret_cast<const float4*>(s)[i];
    ushort4 o;
    o.x = f2b(v.x); o.y = f2b(v.y); o.z = f2b(v.z); o.w = f2b(v.w);
    reinterpret_cast<ushort4*>(d)[i] = o;
  }
}

// ---------------- pack bool mask into bits: pm[u] bit j = amask[u*64+j]!=0 ----------------
__global__ void pack_mask(const unsigned char* __restrict__ am, u64* __restrict__ pm, int nU) {
  int lane = threadIdx.x & 63;
  int wid = blockIdx.x * (blockDim.x >> 6) + (threadIdx.x >> 6);
  int stride = gridDim.x * (blockDim.x >> 6);
  for (int u = wid; u < nU; u += stride) {
    unsigned char v = am[(size_t)u * 64 + lane];
    u64 m = __ballot(v != 0);
    if (lane == 0) pm[u] = m;
  }
}

// ---------------- GEMM: C[M][N] = A[M][K] @ B[N][K]^T ----------------
// MODE 0: f32 out [M][N] + bias.  MODE 1: bf16 out in heads layout [b][h][s][64]
// (row=token b*2048+s, col=h*64+dk).  MODE 2: bf16 out Vt layout [b][h][dk][s]
// (row=d=h*64+dk, col=token b*2048+s).   (S=2048, H=16 hardcoded.)
template<int MODE>
__global__ __launch_bounds__(256) void gemm_bt(
    const unsigned short* __restrict__ A,
    const unsigned short* __restrict__ Bw,
    unsigned short* __restrict__ Cb,
    float* __restrict__ Cf,
    const float* __restrict__ bias,
    int M, int N, int K)
{
  __shared__ unsigned short As[128*32];
  __shared__ unsigned short Bs[128*32];
  const int tid  = threadIdx.x;
  const int w    = tid >> 6, lane = tid & 63;
  const int wr   = w >> 1,   wc   = w & 1;
  const int g    = lane >> 4, li  = lane & 15;
  const int m0   = blockIdx.x * 128, n0 = blockIdx.y * 128;

  f32x4 acc[4][4] = {};

  const int rS0 = (w*2+0)*16 + (lane>>2);
  const int rS1 = (w*2+1)*16 + (lane>>2);
  const int cS  = (lane&3)*8;
  const unsigned short* gA0 = A  + (size_t)(m0+rS0)*K + cS;
  const unsigned short* gA1 = A  + (size_t)(m0+rS1)*K + cS;
  const unsigned short* gB0 = Bw + (size_t)(n0+rS0)*K + cS;
  const unsigned short* gB1 = Bw + (size_t)(n0+rS1)*K + cS;
  unsigned short* lA0 = &As[(w*2+0)*512];
  unsigned short* lA1 = &As[(w*2+1)*512];
  unsigned short* lB0 = &Bs[(w*2+0)*512];
  unsigned short* lB1 = &Bs[(w*2+1)*512];

  for (int k0 = 0; k0 < K; k0 += 32) {
    gload_lds16(gA0 + k0, lA0);
    gload_lds16(gA1 + k0, lA1);
    gload_lds16(gB0 + k0, lB0);
    gload_lds16(gB1 + k0, lB1);
    __syncthreads();

    bf16x8 af[4], bf[4];
    #pragma unroll
    for (int i = 0; i < 4; ++i)
      af[i] = *(const bf16x8*)(&As[(wr*64 + i*16 + li)*32 + g*8]);
    #pragma unroll
    for (int j = 0; j < 4; ++j)
      bf[j] = *(const bf16x8*)(&Bs[(wc*64 + j*16 + li)*32 + g*8]);
    #pragma unroll
    for (int i = 0; i < 4; ++i)
      #pragma unroll
      for (int j = 0; j < 4; ++j)
        acc[i][j] = MFMA(af[i], bf[j], acc[i][j]);
    __syncthreads();
  }

  #pragma unroll
  for (int i = 0; i < 4; ++i) {
    #pragma unroll
    for (int j = 0; j < 4; ++j) {
      int col = n0 + wc*64 + j*16 + li;
      #pragma unroll
      for (int r = 0; r < 4; ++r) {
        int row = m0 + wr*64 + i*16 + g*4 + r;
        float v = acc[i][j][r];
        if (MODE == 0) {
          Cf[(size_t)row*N + col] = v + bias[col];
        } else if (MODE == 1) {
          size_t addr = (((size_t)(row >> 11) * 16 + (col >> 6)) * 2048 + (row & 2047)) * 64 + (col & 63);
          Cb[addr] = f2b(v);
        } else {
          size_t addr = (((size_t)(col >> 11) * 16 + (row >> 6)) * 64 + (row & 63)) * 2048 + (col & 2047);
          Cb[addr] = f2b(v);
        }
      }
    }
  }
}

// ---------------- Flash attention ----------------
// 4 waves, QBLK=128 (32 q-rows/wave), KVBLK=64. K and Vt staged via
// global_load_lds with XOR-swizzled (16B-slot ^ row&7) layouts.
// QK^T: C[q][kv] (A=Q regs, B=K rows).  PV: O^T[d][q] (A=Vt rows, B=P rows).
__global__ __launch_bounds__(256) void attn_kernel(
    const unsigned short* __restrict__ Qh,   // [B*H][S][64]
    const unsigned short* __restrict__ Kh,   // [B*H][S][64]
    const unsigned short* __restrict__ Vt,   // [B*H][64][S]
    const u64* __restrict__ pmask,           // [B*S][S/64]
    const int* __restrict__ causal_p,
    unsigned short* __restrict__ Ob,         // [B*S][H*64]
    int B, int H, int S)
{
  __shared__ unsigned short Ks [64*64];
  __shared__ unsigned short Vts[64*64];
  __shared__ unsigned short Ps [4][32*64];

  const int tid = threadIdx.x, w = tid >> 6, lane = tid & 63;
  const int g = lane >> 4, li = lane & 15;
  const int nqt = S >> 7;
  int id = blockIdx.x;
  int qt = id % nqt, bh = id / nqt;
  if ((id >> 8) & 1) qt = nqt - 1 - qt;   // pair heavy+light blocks per CU
  const int q0 = qt << 7;
  const int b = bh / H, h = bh % H;
  const size_t baseK = (size_t)bh * S * 64;
  const size_t baseV = (size_t)bh * 64 * S;
  const int causal = causal_p[0];
  const int nkt = S >> 6;

  // Q fragments (A-operand: lane li = q row, cols hf*32+g*8)
  bf16x8 qf[2][2];
  #pragma unroll
  for (int qi = 0; qi < 2; ++qi)
    #pragma unroll
    for (int hf = 0; hf < 2; ++hf)
      qf[qi][hf] = *(const bf16x8*)(Qh + baseK + (size_t)(q0 + w*32 + qi*16 + li)*64 + hf*32 + g*8);

  f32x4 oacc[4][2] = {};                    // [di][qi], O^T[d][q]: col q = qi*16+li
  float mrun[2][4], lrun[2][4];
  #pragma unroll
  for (int qi = 0; qi < 2; ++qi)
    #pragma unroll
    for (int r = 0; r < 4; ++r) { mrun[qi][r] = NEG_INF; lrun[qi][r] = 0.f; }

  const int colk  = (lane & 7) ^ ((lane >> 3) & 7);  // pre-swizzled source slot
  const int ldrow = lane >> 3;
  const int ntile = causal ? (qt*2 + 2) : nkt;
  const int qmax  = q0 + w*32 + 31;

  for (int t = 0; t < ntile; ++t) {
    const int kv0 = t << 6;
    __syncthreads();
    #pragma unroll
    for (int s2 = 0; s2 < 2; ++s2) {
      int u = w*2 + s2;
      gload_lds16(Kh + baseK + (size_t)(kv0 + u*8 + ldrow)*64 + colk*8, &Ks[u*512]);
      gload_lds16(Vt + baseV + (size_t)(u*8 + ldrow)*S + kv0 + colk*8, &Vts[u*512]);
    }
    __syncthreads();
    if (causal && kv0 > qmax) continue;     // barriers all at loop top: safe

    // QK^T
    f32x4 sa[2][4];
    #pragma unroll
    for (int qi = 0; qi < 2; ++qi)
      #pragma unroll
      for (int ni = 0; ni < 4; ++ni)
        sa[qi][ni] = (f32x4){0.f, 0.f, 0.f, 0.f};
    #pragma unroll
    for (int ni = 0; ni < 4; ++ni) {
      int row = ni*16 + li, rx = row & 7;
      bf16x8 k0 = *(const bf16x8*)(&Ks[row*64 + ((g     ^ rx))*8]);
      bf16x8 k1 = *(const bf16x8*)(&Ks[row*64 + (((4+g) ^ rx))*8]);
      #pragma unroll
      for (int qi = 0; qi < 2; ++qi) {
        sa[qi][ni] = MFMA(qf[qi][0], k0, sa[qi][ni]);
        sa[qi][ni] = MFMA(qf[qi][1], k1, sa[qi][ni]);
      }
    }

    float cq[2];
    #pragma unroll
    for (int qi = 0; qi < 2; ++qi) {
      float p[4][4];
      u64 mrow[4];
      #pragma unroll
      for (int r = 0; r < 4; ++r)
        mrow[r] = pmask[((size_t)b*S + (q0 + w*32 + qi*16 + g*4 + r)) * nkt + t];
      #pragma unroll
      for (int ni = 0; ni < 4; ++ni) {
        int kvg = kv0 + ni*16 + li;
        #pragma unroll
        for (int r = 0; r < 4; ++r) {
          int qg = q0 + w*32 + qi*16 + g*4 + r;
          bool dead = (causal && (kvg > qg)) || ((mrow[r] >> (ni*16 + li)) & 1ULL);
          p[ni][r] = dead ? NEG_INF : sa[qi][ni][r] * 0.125f;
        }
      }
      float corr[4];
      #pragma unroll
      for (int r = 0; r < 4; ++r) {
        float mx = fmaxf(fmaxf(p[0][r], p[1][r]), fmaxf(p[2][r], p[3][r]));
        mx = fmaxf(mx, __shfl_xor(mx, 1, 16));
        mx = fmaxf(mx, __shfl_xor(mx, 2, 16));
        mx = fmaxf(mx, __shfl_xor(mx, 4, 16));
        mx = fmaxf(mx, __shfl_xor(mx, 8, 16));
        float mn = fmaxf(mrun[qi][r], mx);
        corr[r] = (mrun[qi][r] == NEG_INF) ? 0.f : __expf(mrun[qi][r] - mn);
        float rs = 0.f;
        #pragma unroll
        for (int ni = 0; ni < 4; ++ni) {
          float pe = (mn == NEG_INF) ? 0.f : __expf(p[ni][r] - mn);
          p[ni][r] = pe;
          rs += pe;
        }
        rs += __shfl_xor(rs, 1, 16);
        rs += __shfl_xor(rs, 2, 16);
        rs += __shfl_xor(rs, 4, 16);
        rs += __shfl_xor(rs, 8, 16);
        lrun[qi][r] = lrun[qi][r] * corr[r] + rs;
        mrun[qi][r] = mn;
      }
      // P -> per-wave LDS [q32][kv64], swizzled
      #pragma unroll
      for (int ni = 0; ni < 4; ++ni)
        #pragma unroll
        for (int r = 0; r < 4; ++r) {
          int q = qi*16 + g*4 + r;
          int slot = (ni*2 + (li >> 3)) ^ (q & 7);
          Ps[w][q*64 + slot*8 + (li & 7)] = f2b(p[ni][r]);
        }
      float sel = (lane&3)==0 ? corr[0] : (lane&3)==1 ? corr[1] : (lane&3)==2 ? corr[2] : corr[3];
      cq[qi] = __shfl(sel, ((li >> 2) << 4) + (li & 3), 64);
    }

    #pragma unroll
    for (int di = 0; di < 4; ++di)
      #pragma unroll
      for (int qi = 0; qi < 2; ++qi) {
        oacc[di][qi][0] *= cq[qi]; oacc[di][qi][1] *= cq[qi];
        oacc[di][qi][2] *= cq[qi]; oacc[di][qi][3] *= cq[qi];
      }

    // PV
    #pragma unroll
    for (int c = 0; c < 2; ++c) {
      bf16x8 pf[2];
      #pragma unroll
      for (int qi = 0; qi < 2; ++qi) {
        int q = qi*16 + li;
        pf[qi] = *(const bf16x8*)(&Ps[w][q*64 + (((c*4+g) ^ (q&7)))*8]);
      }
      #pragma unroll
      for (int di = 0; di < 4; ++di) {
        int d = di*16 + li;
        bf16x8 vf = *(const bf16x8*)(&Vts[d*64 + (((c*4+g) ^ (d&7)))*8]);
        #pragma unroll
        for (int qi = 0; qi < 2; ++qi)
          oacc[di][qi] = MFMA(vf, pf[qi], oacc[di][qi]);
      }
    }
  }

  // epilogue: 1/l per q-col, transpose O^T->O via wave-private Ps, coalesced store
  float rl[2];
  #pragma unroll
  for (int qi = 0; qi < 2; ++qi) {
    float sel = (lane&3)==0 ? lrun[qi][0] : (lane&3)==1 ? lrun[qi][1] : (lane&3)==2 ? lrun[qi][2] : lrun[qi][3];
    float lq = __shfl(sel, ((li >> 2) << 4) + (li & 3), 64);
    rl[qi] = (lq > 0.f) ? 1.0f / lq : 0.f;
  }
  #pragma unroll
  for (int di = 0; di < 4; ++di)
    #pragma unroll
    for (int qi = 0; qi < 2; ++qi)
      #pragma unroll
      for (int r = 0; r < 4; ++r) {
        int q = qi*16 + li;
        int d = di*16 + g*4 + r;
        int slot = (d >> 3) ^ (q & 7);
        Ps[w][q*64 + slot*8 + (d & 7)] = f2b(oacc[di][qi][r] * rl[qi]);
      }
  const int D = H * 64;
  #pragma unroll
  for (int rr = 0; rr < 4; ++rr) {
    int q = rr*8 + (lane >> 3);
    int sl = lane & 7;
    bf16x8 v = *(const bf16x8*)(&Ps[w][q*64 + ((sl ^ (q & 7)))*8]);
    *(bf16x8*)(Ob + (size_t)(b*S + q0 + w*32 + q)*D + h*64 + sl*8) = v;
  }
}

extern "C" void kernel_launch(void* const* d_in, const int* in_sizes, int n_in,
                              void* d_out, int out_size, void* d_ws, size_t ws_size,
                              hipStream_t stream) {
  const float* query = (const float*)d_in[0];
  const float* key_  = (const float*)d_in[1];
  const float* value = (const float*)d_in[2];
  const unsigned char* amask = (const unsigned char*)d_in[3];
  const float* Wq   = (const float*)d_in[4];
  const float* Wk   = (const float*)d_in[5];
  const float* Wv   = (const float*)d_in[6];
  const float* Wout = (const float*)d_in[7];
  const float* b_out = (const float*)d_in[8];
  const int* is_causal = (const int*)d_in[9];
  float* out = (float*)d_out;

  const int B = 2, S = 2048, D = 1024, H = 16;
  const int M = B * S;                 // 4096
  const size_t nx = (size_t)M * D;
  const size_t nw = (size_t)D * D;
  const int nU = B * S * (S / 64);     // 131072 packed-mask words

  unsigned short* ws = (unsigned short*)d_ws;
  unsigned short* xq = ws;
  unsigned short* xk = xq + nx;
  unsigned short* xv = xk + nx;
  unsigned short* wq = xv + nx;
  unsigned short* wk = wq + nw;
  unsigned short* wv = wk + nw;
  unsigned short* wo = wv + nw;
  unsigned short* qb = wo + nw;        // [b][h][s][64]
  unsigned short* kb = qb + nx;        // [b][h][s][64]
  unsigned short* vt = kb + nx;        // [b][h][64][s]
  unsigned short* ob = xq;             // reuse: xq dead after Q-projection
  u64* pmask = (u64*)xv;               // reuse: xv dead after V-projection

  cvt7<<<dim3((unsigned)(nx/4/256), 7), 256, 0, stream>>>(
      query, key_, value, Wq, Wk, Wv, Wout,
      xq, xk, xv, wq, wk, wv, wo, (int)(nx/4), (int)(nw/4));

  dim3 gg(M/128, D/128);
  gemm_bt<1><<<gg, 256, 0, stream>>>(xq, wq, qb, nullptr, nullptr, M, D, D);
  gemm_bt<1><<<gg, 256, 0, stream>>>(xk, wk, kb, nullptr, nullptr, M, D, D);
  gemm_bt<2><<<dim3(D/128, M/128), 256, 0, stream>>>(wv, xv, vt, nullptr, nullptr, D, M, D);

  pack_mask<<<512, 256, 0, stream>>>(amask, pmask, nU);

  attn_kernel<<<dim3((S/128) * B * H), 256, 0, stream>>>(qb, kb, vt, pmask, is_causal, ob, B, H, S);

  gemm_bt<0><<<gg, 256, 0, stream>>>(ob, wo, nullptr, out, b_out, M, D, D);
}

// Round 3
// 246.994 us; speedup vs baseline: 1.2831x; 1.0625x over previous
//
#include <hip/hip_runtime.h>

typedef __attribute__((ext_vector_type(8))) short bf16x8;
typedef __attribute__((ext_vector_type(4))) float f32x4;
typedef unsigned long long u64;
typedef unsigned int u32;

#define MFMA(a,b,c) __builtin_amdgcn_mfma_f32_16x16x32_bf16(a,b,c,0,0,0)
#define NEG_INF (-__builtin_inff())
#define SCALE2 0.1803368801111244f   // 0.125 * log2(e)

__device__ __forceinline__ unsigned short f2b(float f) {
  unsigned int u = __float_as_uint(f);
  u = u + 0x7fffu + ((u >> 16) & 1u);
  return (unsigned short)(u >> 16);
}

__device__ __forceinline__ void gload_lds16(const unsigned short* g, unsigned short* l) {
  __builtin_amdgcn_global_load_lds((const __attribute__((address_space(1))) void*)g,
                                   (__attribute__((address_space(3))) void*)l, 16, 0, 0);
}

// ---------------- fused fp32 -> bf16 conversion for all 7 tensors ----------------
__global__ void cvt7(const float* s0, const float* s1, const float* s2,
                     const float* s3, const float* s4, const float* s5, const float* s6,
                     unsigned short* d0, unsigned short* d1, unsigned short* d2,
                     unsigned short* d3, unsigned short* d4, unsigned short* d5, unsigned short* d6,
                     int nbig, int nsmall) {
  const float* s; unsigned short* d; int n4;
  switch (blockIdx.y) {
    case 0: s=s0; d=d0; n4=nbig; break;
    case 1: s=s1; d=d1; n4=nbig; break;
    case 2: s=s2; d=d2; n4=nbig; break;
    case 3: s=s3; d=d3; n4=nsmall; break;
    case 4: s=s4; d=d4; n4=nsmall; break;
    case 5: s=s5; d=d5; n4=nsmall; break;
    default: s=s6; d=d6; n4=nsmall; break;
  }
  int i = blockIdx.x * blockDim.x + threadIdx.x;
  if (i < n4) {
    float4 v = reinterpret_cast<const float4*>(s)[i];
    ushort4 o;
    o.x = f2b(v.x); o.y = f2b(v.y); o.z = f2b(v.z); o.w = f2b(v.w);
    reinterpret_cast<ushort4*>(d)[i] = o;
  }
}

// ---------------- pack bool mask into bits: pm[u] bit j = amask[u*64+j]!=0 ----------------
__global__ void pack_mask(const unsigned char* __restrict__ am, u64* __restrict__ pm, int nU) {
  int lane = threadIdx.x & 63;
  int wid = blockIdx.x * (blockDim.x >> 6) + (threadIdx.x >> 6);
  int stride = gridDim.x * (blockDim.x >> 6);
  for (int u = wid; u < nU; u += stride) {
    unsigned char v = am[(size_t)u * 64 + lane];
    u64 m = __ballot(v != 0);
    if (lane == 0) pm[u] = m;
  }
}

// ---------------- per-row tile summary: ms[row] bit t = any mask bit in tile t ----------------
__global__ void mask_summary(const u64* __restrict__ pm, u32* __restrict__ ms, int rows, int nkt) {
  int lane = threadIdx.x & 63;
  int wid = (blockIdx.x * blockDim.x + threadIdx.x) >> 6;
  int nw = (gridDim.x * blockDim.x) >> 6;
  for (int rp = wid; rp < (rows >> 1); rp += nw) {
    int row = rp * 2 + (lane >> 5);
    int t = lane & 31;
    u64 v = pm[(size_t)row * nkt + t];
    u64 bm = __ballot(v != 0ULL);
    if (lane == 0)  ms[rp*2]     = (u32)bm;
    if (lane == 32) ms[rp*2 + 1] = (u32)(bm >> 32);
  }
}

// ---------------- GEMM: C[M][N] = A[M][K] @ B[N][K]^T ----------------
// MODE 0: f32 out [M][N] + bias.  MODE 1: bf16 out heads layout [b][h][s][64].
// MODE 2: bf16 out Vt layout [b][h][dk][s].   (S=2048, H=16 hardcoded.)
template<int MODE>
__global__ __launch_bounds__(256) void gemm_bt(
    const unsigned short* __restrict__ A,
    const unsigned short* __restrict__ Bw,
    unsigned short* __restrict__ Cb,
    float* __restrict__ Cf,
    const float* __restrict__ bias,
    int M, int N, int K)
{
  __shared__ unsigned short As[128*32];
  __shared__ unsigned short Bs[128*32];
  const int tid  = threadIdx.x;
  const int w    = tid >> 6, lane = tid & 63;
  const int wr   = w >> 1,   wc   = w & 1;
  const int g    = lane >> 4, li  = lane & 15;
  const int m0   = blockIdx.x * 128, n0 = blockIdx.y * 128;

  f32x4 acc[4][4] = {};

  const int rS0 = (w*2+0)*16 + (lane>>2);
  const int rS1 = (w*2+1)*16 + (lane>>2);
  const int cS  = (lane&3)*8;
  const unsigned short* gA0 = A  + (size_t)(m0+rS0)*K + cS;
  const unsigned short* gA1 = A  + (size_t)(m0+rS1)*K + cS;
  const unsigned short* gB0 = Bw + (size_t)(n0+rS0)*K + cS;
  const unsigned short* gB1 = Bw + (size_t)(n0+rS1)*K + cS;
  unsigned short* lA0 = &As[(w*2+0)*512];
  unsigned short* lA1 = &As[(w*2+1)*512];
  unsigned short* lB0 = &Bs[(w*2+0)*512];
  unsigned short* lB1 = &Bs[(w*2+1)*512];

  for (int k0 = 0; k0 < K; k0 += 32) {
    gload_lds16(gA0 + k0, lA0);
    gload_lds16(gA1 + k0, lA1);
    gload_lds16(gB0 + k0, lB0);
    gload_lds16(gB1 + k0, lB1);
    __syncthreads();

    bf16x8 af[4], bf[4];
    #pragma unroll
    for (int i = 0; i < 4; ++i)
      af[i] = *(const bf16x8*)(&As[(wr*64 + i*16 + li)*32 + g*8]);
    #pragma unroll
    for (int j = 0; j < 4; ++j)
      bf[j] = *(const bf16x8*)(&Bs[(wc*64 + j*16 + li)*32 + g*8]);
    #pragma unroll
    for (int i = 0; i < 4; ++i)
      #pragma unroll
      for (int j = 0; j < 4; ++j)
        acc[i][j] = MFMA(af[i], bf[j], acc[i][j]);
    __syncthreads();
  }

  #pragma unroll
  for (int i = 0; i < 4; ++i) {
    #pragma unroll
    for (int j = 0; j < 4; ++j) {
      int col = n0 + wc*64 + j*16 + li;
      #pragma unroll
      for (int r = 0; r < 4; ++r) {
        int row = m0 + wr*64 + i*16 + g*4 + r;
        float v = acc[i][j][r];
        if (MODE == 0) {
          Cf[(size_t)row*N + col] = v + bias[col];
        } else if (MODE == 1) {
          size_t addr = (((size_t)(row >> 11) * 16 + (col >> 6)) * 2048 + (row & 2047)) * 64 + (col & 63);
          Cb[addr] = f2b(v);
        } else {
          size_t addr = (((size_t)(col >> 11) * 16 + (row >> 6)) * 64 + (row & 63)) * 2048 + (col & 2047);
          Cb[addr] = f2b(v);
        }
      }
    }
  }
}

// ---------------- Flash attention ----------------
// QBLK=64, 4 waves x 16 q-rows, KVBLK=64, grid (S/64)*B*H with XCD-aware
// mapping. Fast path for clean tiles (no causal, no mask): 2 VALU/element.
// QK^T: C[q][kv] (A=Q regs, B=K rows).  PV: O^T[d][q] (A=Vt rows, B=P rows).
__global__ __launch_bounds__(256, 4) void attn_kernel(
    const unsigned short* __restrict__ Qh,   // [B*H][S][64]
    const unsigned short* __restrict__ Kh,   // [B*H][S][64]
    const unsigned short* __restrict__ Vt,   // [B*H][64][S]
    const u64* __restrict__ pmask,           // [B*S][S/64]
    const u32* __restrict__ msum,            // [B*S] tile summary
    const int* __restrict__ causal_p,
    unsigned short* __restrict__ Ob,         // [B*S][H*64]
    int B, int H, int S)
{
  __shared__ unsigned short Ks [64*64];
  __shared__ unsigned short Vts[64*64];
  __shared__ unsigned short Ps [4][16*64];

  const int tid = threadIdx.x, w = tid >> 6, lane = tid & 63;
  const int g = lane >> 4, li = lane & 15;
  const int nkt = S >> 6, nqt = S >> 6;

  // XCD-aware mapping: xcd = id&7 handles bh in {xcd, xcd+8, ...}, all qt.
  int id = blockIdx.x;
  int xcd = id & 7, k = id >> 3;
  int grp = k / nqt, qt = k % nqt;
  if (grp & 1) qt = nqt - 1 - qt;          // zig-zag for causal balance
  int bh = xcd + 8 * grp;
  const int q0 = qt << 6;
  const int b = bh / H, h = bh % H;
  const size_t baseK = (size_t)bh * S * 64;
  const size_t baseV = (size_t)bh * 64 * S;
  const int causal = causal_p[0];

  // Q fragments (A-operand: lane li = q row, cols hf*32+g*8)
  const unsigned short* qp = Qh + baseK + (size_t)(q0 + w*16 + li)*64 + g*8;
  const bf16x8 qf0 = *(const bf16x8*)(qp);
  const bf16x8 qf1 = *(const bf16x8*)(qp + 32);

  // per-row mask-tile summary (rows g*4+r of this wave), OR'd
  u32 sOr;
  {
    int qr = q0 + w*16 + g*4;
    u32 s0 = msum[(size_t)b*S + qr + 0];
    u32 s1 = msum[(size_t)b*S + qr + 1];
    u32 s2_ = msum[(size_t)b*S + qr + 2];
    u32 s3 = msum[(size_t)b*S + qr + 3];
    sOr = s0 | s1 | s2_ | s3;
  }

  f32x4 oacc[4] = {};                       // O^T[d][q]: col q = li, row d = di*16+g*4+r
  float mrun[4] = {-1e30f, -1e30f, -1e30f, -1e30f};
  float lrun[4] = {0.f, 0.f, 0.f, 0.f};

  const int colk  = (lane & 7) ^ ((lane >> 3) & 7);
  const int ldrow = lane >> 3;
  const int ntile = causal ? (qt + 1) : nkt;

  for (int t = 0; t < ntile; ++t) {
    const int kv0 = t << 6;
    __syncthreads();
    #pragma unroll
    for (int s2 = 0; s2 < 2; ++s2) {
      int u = w*2 + s2;
      gload_lds16(Kh + baseK + (size_t)(kv0 + u*8 + ldrow)*64 + colk*8, &Ks[u*512]);
      gload_lds16(Vt + baseV + (size_t)(u*8 + ldrow)*S + kv0 + colk*8, &Vts[u*512]);
    }
    __syncthreads();

    // QK^T
    f32x4 sa[4];
    #pragma unroll
    for (int ni = 0; ni < 4; ++ni) sa[ni] = (f32x4){0.f, 0.f, 0.f, 0.f};
    #pragma unroll
    for (int ni = 0; ni < 4; ++ni) {
      int row = ni*16 + li, rx = row & 7;
      bf16x8 k0 = *(const bf16x8*)(&Ks[row*64 + ((g     ^ rx))*8]);
      bf16x8 k1 = *(const bf16x8*)(&Ks[row*64 + (((4+g) ^ rx))*8]);
      sa[ni] = MFMA(qf0, k0, sa[ni]);
      sa[ni] = MFMA(qf1, k1, sa[ni]);
    }

    const bool edge   = (causal != 0) && (t == ntile - 1);
    const bool doMask = __any(((sOr >> t) & 1u) != 0u);
    float corr[4];

    if (!edge && !doMask) {
      // fast path: p = exp2(fma(s, SCALE2, -m))
      #pragma unroll
      for (int r = 0; r < 4; ++r) {
        float mx = fmaxf(fmaxf(sa[0][r], sa[1][r]), fmaxf(sa[2][r], sa[3][r]));
        mx = fmaxf(mx, __shfl_xor(mx, 1, 16));
        mx = fmaxf(mx, __shfl_xor(mx, 2, 16));
        mx = fmaxf(mx, __shfl_xor(mx, 4, 16));
        mx = fmaxf(mx, __shfl_xor(mx, 8, 16));
        float mu = fmaxf(mrun[r], mx * SCALE2);
        corr[r] = exp2f(mrun[r] - mu);
        float rs = 0.f;
        #pragma unroll
        for (int ni = 0; ni < 4; ++ni) {
          float pe = exp2f(fmaf(sa[ni][r], SCALE2, -mu));
          sa[ni][r] = pe;
          rs += pe;
        }
        rs += __shfl_xor(rs, 1, 16);
        rs += __shfl_xor(rs, 2, 16);
        rs += __shfl_xor(rs, 4, 16);
        rs += __shfl_xor(rs, 8, 16);
        lrun[r] = lrun[r] * corr[r] + rs;
        mrun[r] = mu;
      }
    } else {
      u64 mrow[4];
      #pragma unroll
      for (int r = 0; r < 4; ++r)
        mrow[r] = doMask ? pmask[((size_t)b*S + (q0 + w*16 + g*4 + r)) * nkt + t] : 0ULL;
      float s2v[4][4];
      #pragma unroll
      for (int ni = 0; ni < 4; ++ni) {
        int kvg = kv0 + ni*16 + li;
        #pragma unroll
        for (int r = 0; r < 4; ++r) {
          int qg = q0 + w*16 + g*4 + r;
          bool dead = (edge && (kvg > qg)) || ((mrow[r] >> (ni*16 + li)) & 1ULL);
          s2v[ni][r] = dead ? NEG_INF : sa[ni][r] * SCALE2;
        }
      }
      #pragma unroll
      for (int r = 0; r < 4; ++r) {
        float mx = fmaxf(fmaxf(s2v[0][r], s2v[1][r]), fmaxf(s2v[2][r], s2v[3][r]));
        mx = fmaxf(mx, __shfl_xor(mx, 1, 16));
        mx = fmaxf(mx, __shfl_xor(mx, 2, 16));
        mx = fmaxf(mx, __shfl_xor(mx, 4, 16));
        mx = fmaxf(mx, __shfl_xor(mx, 8, 16));
        float mu = fmaxf(mrun[r], mx);      // >= -1e30, finite
        corr[r] = exp2f(mrun[r] - mu);
        float rs = 0.f;
        #pragma unroll
        for (int ni = 0; ni < 4; ++ni) {
          float pe = exp2f(s2v[ni][r] - mu);
          sa[ni][r] = pe;
          rs += pe;
        }
        rs += __shfl_xor(rs, 1, 16);
        rs += __shfl_xor(rs, 2, 16);
        rs += __shfl_xor(rs, 4, 16);
        rs += __shfl_xor(rs, 8, 16);
        lrun[r] = lrun[r] * corr[r] + rs;
        mrun[r] = mu;
      }
    }

    // P -> per-wave LDS [q16][kv64], swizzled
    #pragma unroll
    for (int ni = 0; ni < 4; ++ni)
      #pragma unroll
      for (int r = 0; r < 4; ++r) {
        int q = g*4 + r;
        int slot = (ni*2 + (li >> 3)) ^ (q & 7);
        Ps[w][q*64 + slot*8 + (li & 7)] = f2b(sa[ni][r]);
      }

    // publish correction to q=li layout, rescale O^T
    float sel = (lane&3)==0 ? corr[0] : (lane&3)==1 ? corr[1] : (lane&3)==2 ? corr[2] : corr[3];
    float cq = __shfl(sel, ((li >> 2) << 4) + (li & 3), 64);
    #pragma unroll
    for (int di = 0; di < 4; ++di) {
      oacc[di][0] *= cq; oacc[di][1] *= cq;
      oacc[di][2] *= cq; oacc[di][3] *= cq;
    }

    // PV
    #pragma unroll
    for (int c = 0; c < 2; ++c) {
      int q = li;
      bf16x8 pf = *(const bf16x8*)(&Ps[w][q*64 + (((c*4+g) ^ (q&7)))*8]);
      #pragma unroll
      for (int di = 0; di < 4; ++di) {
        int d = di*16 + li;
        bf16x8 vf = *(const bf16x8*)(&Vts[d*64 + (((c*4+g) ^ (d&7)))*8]);
        oacc[di] = MFMA(vf, pf, oacc[di]);
      }
    }
  }

  // epilogue
  float sel = (lane&3)==0 ? lrun[0] : (lane&3)==1 ? lrun[1] : (lane&3)==2 ? lrun[2] : lrun[3];
  float lq = __shfl(sel, ((li >> 2) << 4) + (li & 3), 64);
  float rl = (lq > 0.f) ? 1.0f / lq : 0.f;
  #pragma unroll
  for (int di = 0; di < 4; ++di)
    #pragma unroll
    for (int r = 0; r < 4; ++r) {
      int q = li;
      int d = di*16 + g*4 + r;
      int slot = (d >> 3) ^ (q & 7);
      Ps[w][q*64 + slot*8 + (d & 7)] = f2b(oacc[di][r] * rl);
    }
  const int D = H * 64;
  #pragma unroll
  for (int rr = 0; rr < 2; ++rr) {
    int q = rr*8 + (lane >> 3);
    int sl = lane & 7;
    bf16x8 v = *(const bf16x8*)(&Ps[w][q*64 + ((sl ^ (q & 7)))*8]);
    *(bf16x8*)(Ob + (size_t)(b*S + q0 + w*16 + q)*D + h*64 + sl*8) = v;
  }
}

extern "C" void kernel_launch(void* const* d_in, const int* in_sizes, int n_in,
                              void* d_out, int out_size, void* d_ws, size_t ws_size,
                              hipStream_t stream) {
  const float* query = (const float*)d_in[0];
  const float* key_  = (const float*)d_in[1];
  const float* value = (const float*)d_in[2];
  const unsigned char* amask = (const unsigned char*)d_in[3];
  const float* Wq   = (const float*)d_in[4];
  const float* Wk   = (const float*)d_in[5];
  const float* Wv   = (const float*)d_in[6];
  const float* Wout = (const float*)d_in[7];
  const float* b_out = (const float*)d_in[8];
  const int* is_causal = (const int*)d_in[9];
  float* out = (float*)d_out;

  const int B = 2, S = 2048, D = 1024, H = 16;
  const int M = B * S;
  const size_t nx = (size_t)M * D;
  const size_t nw = (size_t)D * D;
  const int nU = B * S * (S / 64);

  unsigned short* ws = (unsigned short*)d_ws;
  unsigned short* xq = ws;
  unsigned short* xk = xq + nx;
  unsigned short* xv = xk + nx;
  unsigned short* wq = xv + nx;
  unsigned short* wk = wq + nw;
  unsigned short* wv = wk + nw;
  unsigned short* wo = wv + nw;
  unsigned short* qb = wo + nw;        // [b][h][s][64]
  unsigned short* kb = qb + nx;        // [b][h][s][64]
  unsigned short* vt = kb + nx;        // [b][h][64][s]
  u32* msum = (u32*)(vt + nx);         // [B*S]
  unsigned short* ob = xq;             // reuse: xq dead after Q-projection
  u64* pmask = (u64*)xv;               // reuse: xv dead after V-projection

  cvt7<<<dim3((unsigned)(nx/4/256), 7), 256, 0, stream>>>(
      query, key_, value, Wq, Wk, Wv, Wout,
      xq, xk, xv, wq, wk, wv, wo, (int)(nx/4), (int)(nw/4));

  dim3 gg(M/128, D/128);
  gemm_bt<1><<<gg, 256, 0, stream>>>(xq, wq, qb, nullptr, nullptr, M, D, D);
  gemm_bt<1><<<gg, 256, 0, stream>>>(xk, wk, kb, nullptr, nullptr, M, D, D);
  gemm_bt<2><<<dim3(D/128, M/128), 256, 0, stream>>>(wv, xv, vt, nullptr, nullptr, D, M, D);

  pack_mask<<<512, 256, 0, stream>>>(amask, pmask, nU);
  mask_summary<<<128, 256, 0, stream>>>(pmask, msum, M, S/64);

  attn_kernel<<<dim3((S/64) * B * H), 256, 0, stream>>>(qb, kb, vt, pmask, msum, is_causal, ob, B, H, S);

  gemm_bt<0><<<gg, 256, 0, stream>>>(ob, wo, nullptr, out, b_out, M, D, D);
}

// Round 4
// 233.842 us; speedup vs baseline: 1.3553x; 1.0562x over previous
//
#include <hip/hip_runtime.h>
#include <hip/hip_bf16.h>

typedef __attribute__((ext_vector_type(8))) short bf16x8;
typedef __attribute__((ext_vector_type(4))) float f32x4;
typedef unsigned long long u64;
typedef unsigned int u32;

#define MFMA(a,b,c) __builtin_amdgcn_mfma_f32_16x16x32_bf16(a,b,c,0,0,0)
#define NEG_INF (-__builtin_inff())
#define SCALE2 0.1803368801111244f   // 0.125 * log2(e)

__device__ __forceinline__ unsigned short f2b(float f) {
  unsigned int u = __float_as_uint(f);
  u = u + 0x7fffu + ((u >> 16) & 1u);
  return (unsigned short)(u >> 16);
}

__device__ __forceinline__ u32 pkbf(float lo, float hi) {
  __hip_bfloat162 h = __float22bfloat162_rn(float2{lo, hi});
  return *reinterpret_cast<u32*>(&h);
}

__device__ __forceinline__ void gload_lds16(const unsigned short* g, unsigned short* l) {
  __builtin_amdgcn_global_load_lds((const __attribute__((address_space(1))) void*)g,
                                   (__attribute__((address_space(3))) void*)l, 16, 0, 0);
}

// ---------------- fused fp32 -> bf16 conversion for all 7 tensors ----------------
__global__ void cvt7(const float* s0, const float* s1, const float* s2,
                     const float* s3, const float* s4, const float* s5, const float* s6,
                     unsigned short* d0, unsigned short* d1, unsigned short* d2,
                     unsigned short* d3, unsigned short* d4, unsigned short* d5, unsigned short* d6,
                     int nbig, int nsmall) {
  const float* s; unsigned short* d; int n4;
  switch (blockIdx.y) {
    case 0: s=s0; d=d0; n4=nbig; break;
    case 1: s=s1; d=d1; n4=nbig; break;
    case 2: s=s2; d=d2; n4=nbig; break;
    case 3: s=s3; d=d3; n4=nsmall; break;
    case 4: s=s4; d=d4; n4=nsmall; break;
    case 5: s=s5; d=d5; n4=nsmall; break;
    default: s=s6; d=d6; n4=nsmall; break;
  }
  int i = blockIdx.x * blockDim.x + threadIdx.x;
  if (i < n4) {
    float4 v = reinterpret_cast<const float4*>(s)[i];
    ushort4 o;
    o.x = f2b(v.x); o.y = f2b(v.y); o.z = f2b(v.z); o.w = f2b(v.w);
    reinterpret_cast<ushort4*>(d)[i] = o;
  }
}

// ---------------- pack bool mask into bits ----------------
__global__ void pack_mask(const unsigned char* __restrict__ am, u64* __restrict__ pm, int nU) {
  int lane = threadIdx.x & 63;
  int wid = blockIdx.x * (blockDim.x >> 6) + (threadIdx.x >> 6);
  int stride = gridDim.x * (blockDim.x >> 6);
  for (int u = wid; u < nU; u += stride) {
    unsigned char v = am[(size_t)u * 64 + lane];
    u64 m = __ballot(v != 0);
    if (lane == 0) pm[u] = m;
  }
}

// ---------------- per-row tile summary ----------------
__global__ void mask_summary(const u64* __restrict__ pm, u32* __restrict__ ms, int rows, int nkt) {
  int lane = threadIdx.x & 63;
  int wid = (blockIdx.x * blockDim.x + threadIdx.x) >> 6;
  int nw = (gridDim.x * blockDim.x) >> 6;
  for (int rp = wid; rp < (rows >> 1); rp += nw) {
    int row = rp * 2 + (lane >> 5);
    int t = lane & 31;
    u64 v = pm[(size_t)row * nkt + t];
    u64 bm = __ballot(v != 0ULL);
    if (lane == 0)  ms[rp*2]     = (u32)bm;
    if (lane == 32) ms[rp*2 + 1] = (u32)(bm >> 32);
  }
}

// ---------------- GEMM: C[M][N] = A[M][K] @ B[N][K]^T ----------------
template<int MODE>
__global__ __launch_bounds__(256) void gemm_bt(
    const unsigned short* __restrict__ A,
    const unsigned short* __restrict__ Bw,
    unsigned short* __restrict__ Cb,
    float* __restrict__ Cf,
    const float* __restrict__ bias,
    int M, int N, int K)
{
  __shared__ unsigned short As[128*32];
  __shared__ unsigned short Bs[128*32];
  const int tid  = threadIdx.x;
  const int w    = tid >> 6, lane = tid & 63;
  const int wr   = w >> 1,   wc   = w & 1;
  const int g    = lane >> 4, li  = lane & 15;
  const int m0   = blockIdx.x * 128, n0 = blockIdx.y * 128;

  f32x4 acc[4][4] = {};

  const int rS0 = (w*2+0)*16 + (lane>>2);
  const int rS1 = (w*2+1)*16 + (lane>>2);
  const int cS  = (lane&3)*8;
  const unsigned short* gA0 = A  + (size_t)(m0+rS0)*K + cS;
  const unsigned short* gA1 = A  + (size_t)(m0+rS1)*K + cS;
  const unsigned short* gB0 = Bw + (size_t)(n0+rS0)*K + cS;
  const unsigned short* gB1 = Bw + (size_t)(n0+rS1)*K + cS;
  unsigned short* lA0 = &As[(w*2+0)*512];
  unsigned short* lA1 = &As[(w*2+1)*512];
  unsigned short* lB0 = &Bs[(w*2+0)*512];
  unsigned short* lB1 = &Bs[(w*2+1)*512];

  for (int k0 = 0; k0 < K; k0 += 32) {
    gload_lds16(gA0 + k0, lA0);
    gload_lds16(gA1 + k0, lA1);
    gload_lds16(gB0 + k0, lB0);
    gload_lds16(gB1 + k0, lB1);
    __syncthreads();

    bf16x8 af[4], bf[4];
    #pragma unroll
    for (int i = 0; i < 4; ++i)
      af[i] = *(const bf16x8*)(&As[(wr*64 + i*16 + li)*32 + g*8]);
    #pragma unroll
    for (int j = 0; j < 4; ++j)
      bf[j] = *(const bf16x8*)(&Bs[(wc*64 + j*16 + li)*32 + g*8]);
    #pragma unroll
    for (int i = 0; i < 4; ++i)
      #pragma unroll
      for (int j = 0; j < 4; ++j)
        acc[i][j] = MFMA(af[i], bf[j], acc[i][j]);
    __syncthreads();
  }

  #pragma unroll
  for (int i = 0; i < 4; ++i) {
    #pragma unroll
    for (int j = 0; j < 4; ++j) {
      int col = n0 + wc*64 + j*16 + li;
      #pragma unroll
      for (int r = 0; r < 4; ++r) {
        int row = m0 + wr*64 + i*16 + g*4 + r;
        float v = acc[i][j][r];
        if (MODE == 0) {
          Cf[(size_t)row*N + col] = v + bias[col];
        } else if (MODE == 1) {
          size_t addr = (((size_t)(row >> 11) * 16 + (col >> 6)) * 2048 + (row & 2047)) * 64 + (col & 63);
          Cb[addr] = f2b(v);
        } else {
          size_t addr = (((size_t)(col >> 11) * 16 + (row >> 6)) * 64 + (row & 63)) * 2048 + (col & 2047);
          Cb[addr] = f2b(v);
        }
      }
    }
  }
}

// ---------------- Flash attention (swapped QK^T, in-register P) ----------------
// QBLK=64, 4 waves x 16 q-rows. S^T = mfma(K, Q): lane holds row q=li,
// kv = ni*16+g*4+r. Softmax lane-local + 2 shfl. PV B-frag built in-register
// via 6 shfl_xor per chunk. O^T via mfma(Vt, P).
__global__ __launch_bounds__(256, 4) void attn_kernel(
    const unsigned short* __restrict__ Qh,   // [B*H][S][64]
    const unsigned short* __restrict__ Kh,   // [B*H][S][64]
    const unsigned short* __restrict__ Vt,   // [B*H][64][S]
    const u64* __restrict__ pmask,           // [B*S][S/64]
    const u32* __restrict__ msum,            // [B*S] tile summary
    const int* __restrict__ causal_p,
    unsigned short* __restrict__ Ob,         // [B*S][H*64]
    int B, int H, int S)
{
  __shared__ unsigned short Ks [64*64];
  __shared__ unsigned short Vts[64*64];

  const int tid = threadIdx.x, w = tid >> 6, lane = tid & 63;
  const int g = lane >> 4, li = lane & 15;
  const int nkt = S >> 6, nqt = S >> 6;
  const int causal = causal_p[0];

  // balanced bijective mapping: consecutive ids pair (qh, nqt-1-qh), share bh
  int id = blockIdx.x;
  int par = id & 1;
  int m_  = id >> 1;
  int qh  = m_ & ((nqt >> 1) - 1);
  int bh  = m_ >> 4;                       // nqt/2 = 16 -> shift 4
  int qt  = par ? (nqt - 1 - qh) : qh;
  const int q0 = qt << 6;
  const int b = bh / H, h = bh % H;
  const size_t baseK = (size_t)bh * S * 64;
  const size_t baseV = (size_t)bh * 64 * S;

  // Q fragments (B-operand: lane li = q row, k-cols g*8 / 32+g*8)
  const int qg = q0 + w*16 + li;           // this lane's q row
  const unsigned short* qp = Qh + baseK + (size_t)qg*64 + g*8;
  const bf16x8 qf0 = *(const bf16x8*)(qp);
  const bf16x8 qf1 = *(const bf16x8*)(qp + 32);

  const u32 sOr = msum[(size_t)b*S + qg];

  f32x4 oacc[4] = {};                      // O^T[d][q]: d = di*16+g*4+r, q = li
  float mrun = -1e30f, lrun = 0.f;

  const int colk  = (lane & 7) ^ ((lane >> 3) & 7);
  const int ldrow = lane >> 3;
  const int ntile = causal ? (qt + 1) : nkt;

  for (int t = 0; t < ntile; ++t) {
    const int kv0 = t << 6;
    __syncthreads();
    #pragma unroll
    for (int s2 = 0; s2 < 2; ++s2) {
      int u = w*2 + s2;
      gload_lds16(Kh + baseK + (size_t)(kv0 + u*8 + ldrow)*64 + colk*8, &Ks[u*512]);
      gload_lds16(Vt + baseV + (size_t)(u*8 + ldrow)*S + kv0 + colk*8, &Vts[u*512]);
    }
    __syncthreads();

    // S^T = K * Q^T : sa[ni][r] = S[q=li][kv = kv0 + ni*16 + g*4 + r]
    f32x4 sa[4];
    #pragma unroll
    for (int ni = 0; ni < 4; ++ni) sa[ni] = (f32x4){0.f, 0.f, 0.f, 0.f};
    #pragma unroll
    for (int ni = 0; ni < 4; ++ni) {
      int row = ni*16 + li, rx = row & 7;
      bf16x8 k0 = *(const bf16x8*)(&Ks[row*64 + ((g     ^ rx))*8]);
      bf16x8 k1 = *(const bf16x8*)(&Ks[row*64 + (((4+g) ^ rx))*8]);
      sa[ni] = MFMA(k0, qf0, sa[ni]);
      sa[ni] = MFMA(k1, qf1, sa[ni]);
    }

    const bool edge   = (causal != 0) && (t == ntile - 1);
    const bool doMask = __any(((sOr >> t) & 1u) != 0u);
    float corr;

    if (!edge && !doMask) {
      float mx = sa[0][0];
      #pragma unroll
      for (int ni = 0; ni < 4; ++ni)
        #pragma unroll
        for (int r = 0; r < 4; ++r)
          if (ni + r) mx = fmaxf(mx, sa[ni][r]);
      mx = fmaxf(mx, __shfl_xor(mx, 16));
      mx = fmaxf(mx, __shfl_xor(mx, 32));
      float mu = fmaxf(mrun, mx * SCALE2);
      corr = exp2f(mrun - mu);
      float rs = 0.f;
      #pragma unroll
      for (int ni = 0; ni < 4; ++ni)
        #pragma unroll
        for (int r = 0; r < 4; ++r) {
          float pe = exp2f(fmaf(sa[ni][r], SCALE2, -mu));
          sa[ni][r] = pe;
          rs += pe;
        }
      rs += __shfl_xor(rs, 16);
      rs += __shfl_xor(rs, 32);
      lrun = lrun * corr + rs;
      mrun = mu;
    } else {
      u64 mrow = doMask ? pmask[((size_t)b*S + qg) * nkt + t] : 0ULL;
      #pragma unroll
      for (int ni = 0; ni < 4; ++ni)
        #pragma unroll
        for (int r = 0; r < 4; ++r) {
          int kvloc = ni*16 + g*4 + r;
          bool dead = (edge && (kv0 + kvloc > qg)) || ((mrow >> kvloc) & 1ULL);
          sa[ni][r] = dead ? NEG_INF : sa[ni][r] * SCALE2;
        }
      float mx = sa[0][0];
      #pragma unroll
      for (int ni = 0; ni < 4; ++ni)
        #pragma unroll
        for (int r = 0; r < 4; ++r)
          if (ni + r) mx = fmaxf(mx, sa[ni][r]);
      mx = fmaxf(mx, __shfl_xor(mx, 16));
      mx = fmaxf(mx, __shfl_xor(mx, 32));
      float mu = fmaxf(mrun, mx);
      corr = exp2f(mrun - mu);
      float rs = 0.f;
      #pragma unroll
      for (int ni = 0; ni < 4; ++ni)
        #pragma unroll
        for (int r = 0; r < 4; ++r) {
          float pe = exp2f(sa[ni][r] - mu);
          sa[ni][r] = pe;
          rs += pe;
        }
      rs += __shfl_xor(rs, 16);
      rs += __shfl_xor(rs, 32);
      lrun = lrun * corr + rs;
      mrun = mu;
    }

    // build PV B-fragments in-register: pf[c] = P[q=li][kv = c*32 + g*8 + j]
    bf16x8 pf[2];
    #pragma unroll
    for (int c = 0; c < 2; ++c) {
      u32 PA0 = pkbf(sa[2*c  ][0], sa[2*c  ][1]);
      u32 PA1 = pkbf(sa[2*c  ][2], sa[2*c  ][3]);
      u32 PB0 = pkbf(sa[2*c+1][0], sa[2*c+1][1]);
      u32 PB1 = pkbf(sa[2*c+1][2], sa[2*c+1][3]);
      u32 X16_0 = (u32)__shfl_xor((int)((g==2) ? PB0 : PA0), 16);
      u32 X16_1 = (u32)__shfl_xor((int)((g==2) ? PB1 : PA1), 16);
      u32 X32_0 = (u32)__shfl_xor((int)((g==0) ? PB0 : PA0), 32);
      u32 X32_1 = (u32)__shfl_xor((int)((g==0) ? PB1 : PA1), 32);
      u32 X48_0 = (u32)__shfl_xor((int)((g==1) ? PB0 : PA0), 48);
      u32 X48_1 = (u32)__shfl_xor((int)((g==1) ? PB1 : PA1), 48);
      union { u32 u[4]; bf16x8 v; } pb;
      pb.u[0] = (g==0) ? PA0   : (g==1) ? X48_0 : (g==2) ? X32_0 : X16_0;
      pb.u[1] = (g==0) ? PA1   : (g==1) ? X48_1 : (g==2) ? X32_1 : X16_1;
      pb.u[2] = (g==0) ? X16_0 : (g==1) ? X32_0 : (g==2) ? X48_0 : PB0;
      pb.u[3] = (g==0) ? X16_1 : (g==1) ? X32_1 : (g==2) ? X48_1 : PB1;
      pf[c] = pb.v;
    }

    // rescale O^T by corr (per-lane, q=li)
    #pragma unroll
    for (int di = 0; di < 4; ++di) {
      oacc[di][0] *= corr; oacc[di][1] *= corr;
      oacc[di][2] *= corr; oacc[di][3] *= corr;
    }

    // PV: O^T[d][q] += Vt[d][kv] * P^T[kv][q]
    #pragma unroll
    for (int c = 0; c < 2; ++c) {
      #pragma unroll
      for (int di = 0; di < 4; ++di) {
        int d = di*16 + li;
        bf16x8 vf = *(const bf16x8*)(&Vts[d*64 + (((c*4+g) ^ (d&7)))*8]);
        oacc[di] = MFMA(vf, pf[c], oacc[di]);
      }
    }
  }

  // epilogue: per-lane 1/l (q=li), transpose via LDS scratch, coalesced store
  __syncthreads();                          // all waves done with Ks
  unsigned short* scr = &Ks[w*1024];
  float rl = (lrun > 0.f) ? 1.0f / lrun : 0.f;
  #pragma unroll
  for (int di = 0; di < 4; ++di)
    #pragma unroll
    for (int r = 0; r < 4; ++r) {
      int d = di*16 + g*4 + r;
      scr[li*64 + (((d>>3) ^ (li&7)))*8 + (d&7)] = f2b(oacc[di][r] * rl);
    }
  const int D = H * 64;
  #pragma unroll
  for (int rr = 0; rr < 2; ++rr) {
    int q = rr*8 + (lane >> 3);
    int sl = lane & 7;
    bf16x8 v = *(const bf16x8*)(&scr[q*64 + ((sl ^ (q & 7)))*8]);
    *(bf16x8*)(Ob + (size_t)(b*S + q0 + w*16 + q)*D + h*64 + sl*8) = v;
  }
}

extern "C" void kernel_launch(void* const* d_in, const int* in_sizes, int n_in,
                              void* d_out, int out_size, void* d_ws, size_t ws_size,
                              hipStream_t stream) {
  const float* query = (const float*)d_in[0];
  const float* key_  = (const float*)d_in[1];
  const float* value = (const float*)d_in[2];
  const unsigned char* amask = (const unsigned char*)d_in[3];
  const float* Wq   = (const float*)d_in[4];
  const float* Wk   = (const float*)d_in[5];
  const float* Wv   = (const float*)d_in[6];
  const float* Wout = (const float*)d_in[7];
  const float* b_out = (const float*)d_in[8];
  const int* is_causal = (const int*)d_in[9];
  float* out = (float*)d_out;

  const int B = 2, S = 2048, D = 1024, H = 16;
  const int M = B * S;
  const size_t nx = (size_t)M * D;
  const size_t nw = (size_t)D * D;
  const int nU = B * S * (S / 64);

  unsigned short* ws = (unsigned short*)d_ws;
  unsigned short* xq = ws;
  unsigned short* xk = xq + nx;
  unsigned short* xv = xk + nx;
  unsigned short* wq = xv + nx;
  unsigned short* wk = wq + nw;
  unsigned short* wv = wk + nw;
  unsigned short* wo = wv + nw;
  unsigned short* qb = wo + nw;        // [b][h][s][64]
  unsigned short* kb = qb + nx;        // [b][h][s][64]
  unsigned short* vt = kb + nx;        // [b][h][64][s]
  u32* msum = (u32*)(vt + nx);         // [B*S]
  unsigned short* ob = xq;             // reuse: xq dead after Q-projection
  u64* pmask = (u64*)xv;               // reuse: xv dead after V-projection

  cvt7<<<dim3((unsigned)(nx/4/256), 7), 256, 0, stream>>>(
      query, key_, value, Wq, Wk, Wv, Wout,
      xq, xk, xv, wq, wk, wv, wo, (int)(nx/4), (int)(nw/4));

  dim3 gg(M/128, D/128);
  gemm_bt<1><<<gg, 256, 0, stream>>>(xq, wq, qb, nullptr, nullptr, M, D, D);
  gemm_bt<1><<<gg, 256, 0, stream>>>(xk, wk, kb, nullptr, nullptr, M, D, D);
  gemm_bt<2><<<dim3(D/128, M/128), 256, 0, stream>>>(wv, xv, vt, nullptr, nullptr, D, M, D);

  pack_mask<<<512, 256, 0, stream>>>(amask, pmask, nU);
  mask_summary<<<128, 256, 0, stream>>>(pmask, msum, M, S/64);

  attn_kernel<<<dim3((S/64) * B * H), 256, 0, stream>>>(qb, kb, vt, pmask, msum, is_causal, ob, B, H, S);

  gemm_bt<0><<<gg, 256, 0, stream>>>(ob, wo, nullptr, out, b_out, M, D, D);
}

// Round 8
// 208.353 us; speedup vs baseline: 1.5211x; 1.1223x over previous
//
#include <hip/hip_runtime.h>
#include <hip/hip_bf16.h>

typedef __attribute__((ext_vector_type(8))) short bf16x8;
typedef __attribute__((ext_vector_type(4))) float f32x4;
typedef unsigned long long u64;
typedef unsigned int u32;

#define MFMA(a,b,c) __builtin_amdgcn_mfma_f32_16x16x32_bf16(a,b,c,0,0,0)
#define NEG_INF (-__builtin_inff())
#define SCALE2 0.1803368801111244f   // 0.125 * log2(e)

__device__ __forceinline__ unsigned short f2b(float f) {
  unsigned int u = __float_as_uint(f);
  u = u + 0x7fffu + ((u >> 16) & 1u);
  return (unsigned short)(u >> 16);
}

__device__ __forceinline__ u32 pkbf(float lo, float hi) {
  __hip_bfloat162 h = __float22bfloat162_rn(float2{lo, hi});
  return *reinterpret_cast<u32*>(&h);
}

__device__ __forceinline__ void gload_lds16(const unsigned short* g, unsigned short* l) {
  __builtin_amdgcn_global_load_lds((const __attribute__((address_space(1))) void*)g,
                                   (__attribute__((address_space(3))) void*)l, 16, 0, 0);
}

// ---------------- fused fp32 -> bf16 conversion for all 7 tensors ----------------
__global__ void cvt7(const float* s0, const float* s1, const float* s2,
                     const float* s3, const float* s4, const float* s5, const float* s6,
                     unsigned short* d0, unsigned short* d1, unsigned short* d2,
                     unsigned short* d3, unsigned short* d4, unsigned short* d5, unsigned short* d6,
                     int nbig, int nsmall) {
  const float* s; unsigned short* d; int n4;
  switch (blockIdx.y) {
    case 0: s=s0; d=d0; n4=nbig; break;
    case 1: s=s1; d=d1; n4=nbig; break;
    case 2: s=s2; d=d2; n4=nbig; break;
    case 3: s=s3; d=d3; n4=nsmall; break;
    case 4: s=s4; d=d4; n4=nsmall; break;
    case 5: s=s5; d=d5; n4=nsmall; break;
    default: s=s6; d=d6; n4=nsmall; break;
  }
  int i = blockIdx.x * blockDim.x + threadIdx.x;
  if (i < n4) {
    float4 v = reinterpret_cast<const float4*>(s)[i];
    ushort4 o;
    o.x = f2b(v.x); o.y = f2b(v.y); o.z = f2b(v.z); o.w = f2b(v.w);
    reinterpret_cast<ushort4*>(d)[i] = o;
  }
}

// ---------------- pack bool mask into bits ----------------
__global__ void pack_mask(const unsigned char* __restrict__ am, u64* __restrict__ pm, int nU) {
  int lane = threadIdx.x & 63;
  int wid = blockIdx.x * (blockDim.x >> 6) + (threadIdx.x >> 6);
  int stride = gridDim.x * (blockDim.x >> 6);
  for (int u = wid; u < nU; u += stride) {
    unsigned char v = am[(size_t)u * 64 + lane];
    u64 m = __ballot(v != 0);
    if (lane == 0) pm[u] = m;
  }
}

// ---------------- per-row tile summary ----------------
__global__ void mask_summary(const u64* __restrict__ pm, u32* __restrict__ ms, int rows, int nkt) {
  int lane = threadIdx.x & 63;
  int wid = (blockIdx.x * blockDim.x + threadIdx.x) >> 6;
  int nw = (gridDim.x * blockDim.x) >> 6;
  for (int rp = wid; rp < (rows >> 1); rp += nw) {
    int row = rp * 2 + (lane >> 5);
    int t = lane & 31;
    u64 v = pm[(size_t)row * nkt + t];
    u64 bm = __ballot(v != 0ULL);
    if (lane == 0)  ms[rp*2]     = (u32)bm;
    if (lane == 32) ms[rp*2 + 1] = (u32)(bm >> 32);
  }
}

// ---------------- GEMM: C[M][N] = A[M][K] @ B[N][K]^T ----------------
// MODE 0: f32 out [M][N] + bias.  MODE 1: bf16 out heads layout [b][h][s][64].
// MODE 2: bf16 out Vt layout [b][h][dk][s].   (S=2048, H=16 hardcoded.)
template<int MODE>
__global__ __launch_bounds__(256) void gemm_bt(
    const unsigned short* __restrict__ A,
    const unsigned short* __restrict__ Bw,
    unsigned short* __restrict__ Cb,
    float* __restrict__ Cf,
    const float* __restrict__ bias,
    int M, int N, int K)
{
  __shared__ unsigned short As[128*32];
  __shared__ unsigned short Bs[128*32];
  const int tid  = threadIdx.x;
  const int w    = tid >> 6, lane = tid & 63;
  const int wr   = w >> 1,   wc   = w & 1;
  const int g    = lane >> 4, li  = lane & 15;
  const int m0   = blockIdx.x * 128, n0 = blockIdx.y * 128;

  f32x4 acc[4][4] = {};

  const int rS0 = (w*2+0)*16 + (lane>>2);
  const int rS1 = (w*2+1)*16 + (lane>>2);
  const int cS  = (lane&3)*8;
  const unsigned short* gA0 = A  + (size_t)(m0+rS0)*K + cS;
  const unsigned short* gA1 = A  + (size_t)(m0+rS1)*K + cS;
  const unsigned short* gB0 = Bw + (size_t)(n0+rS0)*K + cS;
  const unsigned short* gB1 = Bw + (size_t)(n0+rS1)*K + cS;
  unsigned short* lA0 = &As[(w*2+0)*512];
  unsigned short* lA1 = &As[(w*2+1)*512];
  unsigned short* lB0 = &Bs[(w*2+0)*512];
  unsigned short* lB1 = &Bs[(w*2+1)*512];

  for (int k0 = 0; k0 < K; k0 += 32) {
    gload_lds16(gA0 + k0, lA0);
    gload_lds16(gA1 + k0, lA1);
    gload_lds16(gB0 + k0, lB0);
    gload_lds16(gB1 + k0, lB1);
    __syncthreads();

    bf16x8 af[4], bf[4];
    #pragma unroll
    for (int i = 0; i < 4; ++i)
      af[i] = *(const bf16x8*)(&As[(wr*64 + i*16 + li)*32 + g*8]);
    #pragma unroll
    for (int j = 0; j < 4; ++j)
      bf[j] = *(const bf16x8*)(&Bs[(wc*64 + j*16 + li)*32 + g*8]);
    #pragma unroll
    for (int i = 0; i < 4; ++i)
      #pragma unroll
      for (int j = 0; j < 4; ++j)
        acc[i][j] = MFMA(af[i], bf[j], acc[i][j]);
    __syncthreads();
  }

  #pragma unroll
  for (int i = 0; i < 4; ++i) {
    #pragma unroll
    for (int j = 0; j < 4; ++j) {
      int col = n0 + wc*64 + j*16 + li;
      #pragma unroll
      for (int r = 0; r < 4; ++r) {
        int row = m0 + wr*64 + i*16 + g*4 + r;
        float v = acc[i][j][r];
        if (MODE == 0) {
          Cf[(size_t)row*N + col] = v + bias[col];
        } else if (MODE == 1) {
          size_t addr = (((size_t)(row >> 11) * 16 + (col >> 6)) * 2048 + (row & 2047)) * 64 + (col & 63);
          Cb[addr] = f2b(v);
        } else {
          size_t addr = (((size_t)(col >> 11) * 16 + (row >> 6)) * 64 + (row & 63)) * 2048 + (col & 2047);
          Cb[addr] = f2b(v);
        }
      }
    }
  }
}

// ---------------- Flash attention (round-4 proven body; balanced remap) ----------------
// QBLK=64, 4 waves x 16 q-rows. S^T = mfma(K, Q): lane holds row q=li,
// kv = ni*16+g*4+r. Softmax lane-local + 2 shfl. PV B-frag built in-register
// via 6 shfl_xor per chunk. O^T via mfma(Vt, P).
__global__ __launch_bounds__(256, 4) void attn_kernel(
    const unsigned short* __restrict__ Qh,   // [B*H][S][64]
    const unsigned short* __restrict__ Kh,   // [B*H][S][64]
    const unsigned short* __restrict__ Vt,   // [B*H][64][S]
    const u64* __restrict__ pmask,           // [B*S][S/64]
    const u32* __restrict__ msum,            // [B*S] tile summary
    const int* __restrict__ causal_p,
    unsigned short* __restrict__ Ob,         // [B*S][H*64]
    int B, int H, int S)
{
  __shared__ unsigned short Ks [64*64];
  __shared__ unsigned short Vts[64*64];

  const int tid = threadIdx.x, w = tid >> 6, lane = tid & 63;
  const int g = lane >> 4, li = lane & 15;
  const int nkt = S >> 6, nqt = S >> 6;
  const int causal = causal_p[0];

  // balanced remap: par/qh mix id bits 0 and 8..9 so any contiguous-4 or
  // stride-256 co-resident set has near-constant total work (66 / 58..74).
  int id = blockIdx.x;
  int par = (id ^ (id >> 8)) & 1;
  int qh  = ((id >> 1) & 15) ^ (((id >> 8) & 3) << 2);
  int bh  = id >> 5;
  int qt  = par ? (nqt - 1 - qh) : qh;
  const int q0 = qt << 6;
  const int b = bh / H, h = bh % H;
  const size_t baseK = (size_t)bh * S * 64;
  const size_t baseV = (size_t)bh * 64 * S;

  // Q fragments (B-operand: lane li = q row, k-cols g*8 / 32+g*8)
  const int qg = q0 + w*16 + li;           // this lane's q row
  const unsigned short* qp = Qh + baseK + (size_t)qg*64 + g*8;
  const bf16x8 qf0 = *(const bf16x8*)(qp);
  const bf16x8 qf1 = *(const bf16x8*)(qp + 32);

  const u32 sOr = msum[(size_t)b*S + qg];

  f32x4 oacc[4] = {};                      // O^T[d][q]: d = di*16+g*4+r, q = li
  float mrun = -1e30f, lrun = 0.f;

  const int colk  = (lane & 7) ^ ((lane >> 3) & 7);
  const int ldrow = lane >> 3;
  const int ntile = causal ? (qt + 1) : nkt;

  for (int t = 0; t < ntile; ++t) {
    const int kv0 = t << 6;
    __syncthreads();
    #pragma unroll
    for (int s2 = 0; s2 < 2; ++s2) {
      int u = w*2 + s2;
      gload_lds16(Kh + baseK + (size_t)(kv0 + u*8 + ldrow)*64 + colk*8, &Ks[u*512]);
      gload_lds16(Vt + baseV + (size_t)(u*8 + ldrow)*S + kv0 + colk*8, &Vts[u*512]);
    }
    __syncthreads();

    // S^T = K * Q^T : sa[ni][r] = S[q=li][kv = kv0 + ni*16 + g*4 + r]
    f32x4 sa[4];
    #pragma unroll
    for (int ni = 0; ni < 4; ++ni) sa[ni] = (f32x4){0.f, 0.f, 0.f, 0.f};
    #pragma unroll
    for (int ni = 0; ni < 4; ++ni) {
      int row = ni*16 + li, rx = row & 7;
      bf16x8 k0 = *(const bf16x8*)(&Ks[row*64 + ((g     ^ rx))*8]);
      bf16x8 k1 = *(const bf16x8*)(&Ks[row*64 + (((4+g) ^ rx))*8]);
      sa[ni] = MFMA(k0, qf0, sa[ni]);
      sa[ni] = MFMA(k1, qf1, sa[ni]);
    }

    const bool edge   = (causal != 0) && (t == ntile - 1);
    const bool doMask = __any(((sOr >> t) & 1u) != 0u);
    float corr;

    if (!edge && !doMask) {
      float mx = sa[0][0];
      #pragma unroll
      for (int ni = 0; ni < 4; ++ni)
        #pragma unroll
        for (int r = 0; r < 4; ++r)
          if (ni + r) mx = fmaxf(mx, sa[ni][r]);
      mx = fmaxf(mx, __shfl_xor(mx, 16));
      mx = fmaxf(mx, __shfl_xor(mx, 32));
      float mu = fmaxf(mrun, mx * SCALE2);
      corr = exp2f(mrun - mu);
      float rs = 0.f;
      #pragma unroll
      for (int ni = 0; ni < 4; ++ni)
        #pragma unroll
        for (int r = 0; r < 4; ++r) {
          float pe = exp2f(fmaf(sa[ni][r], SCALE2, -mu));
          sa[ni][r] = pe;
          rs += pe;
        }
      rs += __shfl_xor(rs, 16);
      rs += __shfl_xor(rs, 32);
      lrun = lrun * corr + rs;
      mrun = mu;
    } else {
      u64 mrow = doMask ? pmask[((size_t)b*S + qg) * nkt + t] : 0ULL;
      #pragma unroll
      for (int ni = 0; ni < 4; ++ni)
        #pragma unroll
        for (int r = 0; r < 4; ++r) {
          int kvloc = ni*16 + g*4 + r;
          bool dead = (edge && (kv0 + kvloc > qg)) || ((mrow >> kvloc) & 1ULL);
          sa[ni][r] = dead ? NEG_INF : sa[ni][r] * SCALE2;
        }
      float mx = sa[0][0];
      #pragma unroll
      for (int ni = 0; ni < 4; ++ni)
        #pragma unroll
        for (int r = 0; r < 4; ++r)
          if (ni + r) mx = fmaxf(mx, sa[ni][r]);
      mx = fmaxf(mx, __shfl_xor(mx, 16));
      mx = fmaxf(mx, __shfl_xor(mx, 32));
      float mu = fmaxf(mrun, mx);
      corr = exp2f(mrun - mu);
      float rs = 0.f;
      #pragma unroll
      for (int ni = 0; ni < 4; ++ni)
        #pragma unroll
        for (int r = 0; r < 4; ++r) {
          float pe = exp2f(sa[ni][r] - mu);
          sa[ni][r] = pe;
          rs += pe;
        }
      rs += __shfl_xor(rs, 16);
      rs += __shfl_xor(rs, 32);
      lrun = lrun * corr + rs;
      mrun = mu;
    }

    // build PV B-fragments in-register: pf[c] = P[q=li][kv = c*32 + g*8 + j]
    bf16x8 pf[2];
    #pragma unroll
    for (int c = 0; c < 2; ++c) {
      u32 PA0 = pkbf(sa[2*c  ][0], sa[2*c  ][1]);
      u32 PA1 = pkbf(sa[2*c  ][2], sa[2*c  ][3]);
      u32 PB0 = pkbf(sa[2*c+1][0], sa[2*c+1][1]);
      u32 PB1 = pkbf(sa[2*c+1][2], sa[2*c+1][3]);
      u32 X16_0 = (u32)__shfl_xor((int)((g==2) ? PB0 : PA0), 16);
      u32 X16_1 = (u32)__shfl_xor((int)((g==2) ? PB1 : PA1), 16);
      u32 X32_0 = (u32)__shfl_xor((int)((g==0) ? PB0 : PA0), 32);
      u32 X32_1 = (u32)__shfl_xor((int)((g==0) ? PB1 : PA1), 32);
      u32 X48_0 = (u32)__shfl_xor((int)((g==1) ? PB0 : PA0), 48);
      u32 X48_1 = (u32)__shfl_xor((int)((g==1) ? PB1 : PA1), 48);
      union { u32 u[4]; bf16x8 v; } pbu;
      pbu.u[0] = (g==0) ? PA0   : (g==1) ? X48_0 : (g==2) ? X32_0 : X16_0;
      pbu.u[1] = (g==0) ? PA1   : (g==1) ? X48_1 : (g==2) ? X32_1 : X16_1;
      pbu.u[2] = (g==0) ? X16_0 : (g==1) ? X32_0 : (g==2) ? X48_0 : PB0;
      pbu.u[3] = (g==0) ? X16_1 : (g==1) ? X32_1 : (g==2) ? X48_1 : PB1;
      pf[c] = pbu.v;
    }

    // rescale O^T by corr (per-lane, q=li)
    #pragma unroll
    for (int di = 0; di < 4; ++di) {
      oacc[di][0] *= corr; oacc[di][1] *= corr;
      oacc[di][2] *= corr; oacc[di][3] *= corr;
    }

    // PV: O^T[d][q] += Vt[d][kv] * P^T[kv][q]
    #pragma unroll
    for (int c = 0; c < 2; ++c) {
      #pragma unroll
      for (int di = 0; di < 4; ++di) {
        int d = di*16 + li;
        bf16x8 vf = *(const bf16x8*)(&Vts[d*64 + (((c*4+g) ^ (d&7)))*8]);
        oacc[di] = MFMA(vf, pf[c], oacc[di]);
      }
    }
  }

  // epilogue: per-lane 1/l (q=li), transpose via LDS scratch, coalesced store
  __syncthreads();                          // all waves done with Ks
  unsigned short* scr = &Ks[w*1024];
  float rl = (lrun > 0.f) ? 1.0f / lrun : 0.f;
  #pragma unroll
  for (int di = 0; di < 4; ++di)
    #pragma unroll
    for (int r = 0; r < 4; ++r) {
      int d = di*16 + g*4 + r;
      scr[li*64 + (((d>>3) ^ (li&7)))*8 + (d&7)] = f2b(oacc[di][r] * rl);
    }
  const int D = H * 64;
  #pragma unroll
  for (int rr = 0; rr < 2; ++rr) {
    int q = rr*8 + (lane >> 3);
    int sl = lane & 7;
    bf16x8 v = *(const bf16x8*)(&scr[q*64 + ((sl ^ (q & 7)))*8]);
    *(bf16x8*)(Ob + (size_t)(b*S + q0 + w*16 + q)*D + h*64 + sl*8) = v;
  }
}

extern "C" void kernel_launch(void* const* d_in, const int* in_sizes, int n_in,
                              void* d_out, int out_size, void* d_ws, size_t ws_size,
                              hipStream_t stream) {
  const float* query = (const float*)d_in[0];
  const float* key_  = (const float*)d_in[1];
  const float* value = (const float*)d_in[2];
  const unsigned char* amask = (const unsigned char*)d_in[3];
  const float* Wq   = (const float*)d_in[4];
  const float* Wk   = (const float*)d_in[5];
  const float* Wv   = (const float*)d_in[6];
  const float* Wout = (const float*)d_in[7];
  const float* b_out = (const float*)d_in[8];
  const int* is_causal = (const int*)d_in[9];
  float* out = (float*)d_out;

  const int B = 2, S = 2048, D = 1024, H = 16;
  const int M = B * S;
  const size_t nx = (size_t)M * D;
  const size_t nw = (size_t)D * D;
  const int nU = B * S * (S / 64);

  unsigned short* ws = (unsigned short*)d_ws;
  unsigned short* xq = ws;
  unsigned short* xk = xq + nx;
  unsigned short* xv = xk + nx;
  unsigned short* wq = xv + nx;
  unsigned short* wk = wq + nw;
  unsigned short* wv = wk + nw;
  unsigned short* wo = wv + nw;
  unsigned short* qb = wo + nw;        // [b][h][s][64]
  unsigned short* kb = qb + nx;        // [b][h][s][64]
  unsigned short* vt = kb + nx;        // [b][h][64][s]
  u32* msum = (u32*)(vt + nx);         // [B*S]
  unsigned short* ob = xq;             // reuse: xq dead after Q-projection
  u64* pmask = (u64*)xv;               // reuse: xv dead after V-projection

  cvt7<<<dim3((unsigned)(nx/4/256), 7), 256, 0, stream>>>(
      query, key_, value, Wq, Wk, Wv, Wout,
      xq, xk, xv, wq, wk, wv, wo, (int)(nx/4), (int)(nw/4));

  dim3 gg(M/128, D/128);
  gemm_bt<1><<<gg, 256, 0, stream>>>(xq, wq, qb, nullptr, nullptr, M, D, D);
  gemm_bt<1><<<gg, 256, 0, stream>>>(xk, wk, kb, nullptr, nullptr, M, D, D);
  gemm_bt<2><<<dim3(D/128, M/128), 256, 0, stream>>>(wv, xv, vt, nullptr, nullptr, D, M, D);

  pack_mask<<<512, 256, 0, stream>>>(amask, pmask, nU);
  mask_summary<<<128, 256, 0, stream>>>(pmask, msum, M, S/64);

  attn_kernel<<<dim3((S/64) * B * H), 256, 0, stream>>>(qb, kb, vt, pmask, msum, is_causal, ob, B, H, S);

  gemm_bt<0><<<gg, 256, 0, stream>>>(ob, wo, nullptr, out, b_out, M, D, D);
}

// Round 9
// 190.133 us; speedup vs baseline: 1.6668x; 1.0958x over previous
//
#include <hip/hip_runtime.h>
#include <hip/hip_bf16.h>

typedef __attribute__((ext_vector_type(8))) short bf16x8;
typedef __attribute__((ext_vector_type(4))) float f32x4;
typedef unsigned long long u64;
typedef unsigned int u32;

#define MFMA(a,b,c) __builtin_amdgcn_mfma_f32_16x16x32_bf16(a,b,c,0,0,0)
#define NEG_INF (-__builtin_inff())
#define SCALE2 0.1803368801111244f   // 0.125 * log2(e)

__device__ __forceinline__ unsigned short f2b(float f) {
  unsigned int u = __float_as_uint(f);
  u = u + 0x7fffu + ((u >> 16) & 1u);
  return (unsigned short)(u >> 16);
}

__device__ __forceinline__ u32 pkbf(float lo, float hi) {
  __hip_bfloat162 h = __float22bfloat162_rn(float2{lo, hi});
  return *reinterpret_cast<u32*>(&h);
}

__device__ __forceinline__ void gload_lds16(const unsigned short* g, unsigned short* l) {
  __builtin_amdgcn_global_load_lds((const __attribute__((address_space(1))) void*)g,
                                   (__attribute__((address_space(3))) void*)l, 16, 0, 0);
}

// ---------------- fused fp32 -> bf16 conversion for all 7 tensors ----------------
__global__ void cvt7(const float* s0, const float* s1, const float* s2,
                     const float* s3, const float* s4, const float* s5, const float* s6,
                     unsigned short* d0, unsigned short* d1, unsigned short* d2,
                     unsigned short* d3, unsigned short* d4, unsigned short* d5, unsigned short* d6,
                     int nbig, int nsmall) {
  const float* s; unsigned short* d; int n4;
  switch (blockIdx.y) {
    case 0: s=s0; d=d0; n4=nbig; break;
    case 1: s=s1; d=d1; n4=nbig; break;
    case 2: s=s2; d=d2; n4=nbig; break;
    case 3: s=s3; d=d3; n4=nsmall; break;
    case 4: s=s4; d=d4; n4=nsmall; break;
    case 5: s=s5; d=d5; n4=nsmall; break;
    default: s=s6; d=d6; n4=nsmall; break;
  }
  int i = blockIdx.x * blockDim.x + threadIdx.x;
  if (i < n4) {
    float4 v = reinterpret_cast<const float4*>(s)[i];
    ushort4 o;
    o.x = f2b(v.x); o.y = f2b(v.y); o.z = f2b(v.z); o.w = f2b(v.w);
    reinterpret_cast<ushort4*>(d)[i] = o;
  }
}

// ---------------- pack bool mask into bits ----------------
__global__ void pack_mask(const unsigned char* __restrict__ am, u64* __restrict__ pm, int nU) {
  int lane = threadIdx.x & 63;
  int wid = blockIdx.x * (blockDim.x >> 6) + (threadIdx.x >> 6);
  int stride = gridDim.x * (blockDim.x >> 6);
  for (int u = wid; u < nU; u += stride) {
    unsigned char v = am[(size_t)u * 64 + lane];
    u64 m = __ballot(v != 0);
    if (lane == 0) pm[u] = m;
  }
}

// ---------------- per-row tile summary ----------------
__global__ void mask_summary(const u64* __restrict__ pm, u32* __restrict__ ms, int rows, int nkt) {
  int lane = threadIdx.x & 63;
  int wid = (blockIdx.x * blockDim.x + threadIdx.x) >> 6;
  int nw = (gridDim.x * blockDim.x) >> 6;
  for (int rp = wid; rp < (rows >> 1); rp += nw) {
    int row = rp * 2 + (lane >> 5);
    int t = lane & 31;
    u64 v = pm[(size_t)row * nkt + t];
    u64 bm = __ballot(v != 0ULL);
    if (lane == 0)  ms[rp*2]     = (u32)bm;
    if (lane == 32) ms[rp*2 + 1] = (u32)(bm >> 32);
  }
}

// ---------------- GEMM 64x128 tile: C[M][N] = A[M][K] @ B[N][K]^T ----------------
// Grid (M/64, N/128) = 512 blocks for our shapes -> 2 blocks/CU, 8 waves/CU.
// MODE 0: f32 out [M][N] + bias.  MODE 1: bf16 out heads layout [b][h][s][64].
// MODE 2: bf16 out Vt layout [b][h][dk][s].   (S=2048, H=16 hardcoded.)
template<int MODE>
__global__ __launch_bounds__(256) void gemm64(
    const unsigned short* __restrict__ A,
    const unsigned short* __restrict__ Bw,
    unsigned short* __restrict__ Cb,
    float* __restrict__ Cf,
    const float* __restrict__ bias,
    int M, int N, int K)
{
  __shared__ unsigned short As[64*32];
  __shared__ unsigned short Bs[128*32];
  const int tid  = threadIdx.x;
  const int w    = tid >> 6, lane = tid & 63;
  const int wr   = w >> 1,   wc   = w & 1;
  const int g    = lane >> 4, li  = lane & 15;
  const int m0   = blockIdx.x * 64, n0 = blockIdx.y * 128;

  f32x4 acc[2][4] = {};
  const int crow = lane >> 2, ccol = (lane & 3) * 8;
  const unsigned short* gA  = A  + (size_t)(m0 + w*16 + crow)*K + ccol;
  const unsigned short* gB0 = Bw + (size_t)(n0 + w*16 + crow)*K + ccol;
  const unsigned short* gB1 = Bw + (size_t)(n0 + (w+4)*16 + crow)*K + ccol;

  for (int k0 = 0; k0 < K; k0 += 32) {
    gload_lds16(gA  + k0, &As[w*512]);
    gload_lds16(gB0 + k0, &Bs[w*512]);
    gload_lds16(gB1 + k0, &Bs[(w+4)*512]);
    __syncthreads();

    bf16x8 af[2], bf[4];
    #pragma unroll
    for (int i = 0; i < 2; ++i)
      af[i] = *(const bf16x8*)(&As[(wr*32 + i*16 + li)*32 + g*8]);
    #pragma unroll
    for (int j = 0; j < 4; ++j)
      bf[j] = *(const bf16x8*)(&Bs[(wc*64 + j*16 + li)*32 + g*8]);
    #pragma unroll
    for (int i = 0; i < 2; ++i)
      #pragma unroll
      for (int j = 0; j < 4; ++j)
        acc[i][j] = MFMA(af[i], bf[j], acc[i][j]);
    __syncthreads();
  }

  #pragma unroll
  for (int i = 0; i < 2; ++i) {
    #pragma unroll
    for (int j = 0; j < 4; ++j) {
      int col = n0 + wc*64 + j*16 + li;
      #pragma unroll
      for (int r = 0; r < 4; ++r) {
        int row = m0 + wr*32 + i*16 + g*4 + r;
        float v = acc[i][j][r];
        if (MODE == 0) {
          Cf[(size_t)row*N + col] = v + bias[col];
        } else if (MODE == 1) {
          size_t addr = (((size_t)(row >> 11) * 16 + (col >> 6)) * 2048 + (row & 2047)) * 64 + (col & 63);
          Cb[addr] = f2b(v);
        } else {
          size_t addr = (((size_t)(col >> 11) * 16 + (row >> 6)) * 64 + (row & 63)) * 2048 + (col & 2047);
          Cb[addr] = f2b(v);
        }
      }
    }
  }
}

// ---------------- Flash attention (round-8 green, verbatim) ----------------
__global__ __launch_bounds__(256, 4) void attn_kernel(
    const unsigned short* __restrict__ Qh,   // [B*H][S][64]
    const unsigned short* __restrict__ Kh,   // [B*H][S][64]
    const unsigned short* __restrict__ Vt,   // [B*H][64][S]
    const u64* __restrict__ pmask,           // [B*S][S/64]
    const u32* __restrict__ msum,            // [B*S] tile summary
    const int* __restrict__ causal_p,
    unsigned short* __restrict__ Ob,         // [B*S][H*64]
    int B, int H, int S)
{
  __shared__ unsigned short Ks [64*64];
  __shared__ unsigned short Vts[64*64];

  const int tid = threadIdx.x, w = tid >> 6, lane = tid & 63;
  const int g = lane >> 4, li = lane & 15;
  const int nkt = S >> 6, nqt = S >> 6;
  const int causal = causal_p[0];

  // balanced remap: par/qh mix id bits 0 and 8..9 so any contiguous-4 or
  // stride-256 co-resident set has near-constant total work (66 / 58..74).
  int id = blockIdx.x;
  int par = (id ^ (id >> 8)) & 1;
  int qh  = ((id >> 1) & 15) ^ (((id >> 8) & 3) << 2);
  int bh  = id >> 5;
  int qt  = par ? (nqt - 1 - qh) : qh;
  const int q0 = qt << 6;
  const int b = bh / H, h = bh % H;
  const size_t baseK = (size_t)bh * S * 64;
  const size_t baseV = (size_t)bh * 64 * S;

  // Q fragments (B-operand: lane li = q row, k-cols g*8 / 32+g*8)
  const int qg = q0 + w*16 + li;           // this lane's q row
  const unsigned short* qp = Qh + baseK + (size_t)qg*64 + g*8;
  const bf16x8 qf0 = *(const bf16x8*)(qp);
  const bf16x8 qf1 = *(const bf16x8*)(qp + 32);

  const u32 sOr = msum[(size_t)b*S + qg];

  f32x4 oacc[4] = {};                      // O^T[d][q]: d = di*16+g*4+r, q = li
  float mrun = -1e30f, lrun = 0.f;

  const int colk  = (lane & 7) ^ ((lane >> 3) & 7);
  const int ldrow = lane >> 3;
  const int ntile = causal ? (qt + 1) : nkt;

  for (int t = 0; t < ntile; ++t) {
    const int kv0 = t << 6;
    __syncthreads();
    #pragma unroll
    for (int s2 = 0; s2 < 2; ++s2) {
      int u = w*2 + s2;
      gload_lds16(Kh + baseK + (size_t)(kv0 + u*8 + ldrow)*64 + colk*8, &Ks[u*512]);
      gload_lds16(Vt + baseV + (size_t)(u*8 + ldrow)*S + kv0 + colk*8, &Vts[u*512]);
    }
    __syncthreads();

    // S^T = K * Q^T : sa[ni][r] = S[q=li][kv = kv0 + ni*16 + g*4 + r]
    f32x4 sa[4];
    #pragma unroll
    for (int ni = 0; ni < 4; ++ni) sa[ni] = (f32x4){0.f, 0.f, 0.f, 0.f};
    #pragma unroll
    for (int ni = 0; ni < 4; ++ni) {
      int row = ni*16 + li, rx = row & 7;
      bf16x8 k0 = *(const bf16x8*)(&Ks[row*64 + ((g     ^ rx))*8]);
      bf16x8 k1 = *(const bf16x8*)(&Ks[row*64 + (((4+g) ^ rx))*8]);
      sa[ni] = MFMA(k0, qf0, sa[ni]);
      sa[ni] = MFMA(k1, qf1, sa[ni]);
    }

    const bool edge   = (causal != 0) && (t == ntile - 1);
    const bool doMask = __any(((sOr >> t) & 1u) != 0u);
    float corr;

    if (!edge && !doMask) {
      float mx = sa[0][0];
      #pragma unroll
      for (int ni = 0; ni < 4; ++ni)
        #pragma unroll
        for (int r = 0; r < 4; ++r)
          if (ni + r) mx = fmaxf(mx, sa[ni][r]);
      mx = fmaxf(mx, __shfl_xor(mx, 16));
      mx = fmaxf(mx, __shfl_xor(mx, 32));
      float mu = fmaxf(mrun, mx * SCALE2);
      corr = exp2f(mrun - mu);
      float rs = 0.f;
      #pragma unroll
      for (int ni = 0; ni < 4; ++ni)
        #pragma unroll
        for (int r = 0; r < 4; ++r) {
          float pe = exp2f(fmaf(sa[ni][r], SCALE2, -mu));
          sa[ni][r] = pe;
          rs += pe;
        }
      rs += __shfl_xor(rs, 16);
      rs += __shfl_xor(rs, 32);
      lrun = lrun * corr + rs;
      mrun = mu;
    } else {
      u64 mrow = doMask ? pmask[((size_t)b*S + qg) * nkt + t] : 0ULL;
      #pragma unroll
      for (int ni = 0; ni < 4; ++ni)
        #pragma unroll
        for (int r = 0; r < 4; ++r) {
          int kvloc = ni*16 + g*4 + r;
          bool dead = (edge && (kv0 + kvloc > qg)) || ((mrow >> kvloc) & 1ULL);
          sa[ni][r] = dead ? NEG_INF : sa[ni][r] * SCALE2;
        }
      float mx = sa[0][0];
      #pragma unroll
      for (int ni = 0; ni < 4; ++ni)
        #pragma unroll
        for (int r = 0; r < 4; ++r)
          if (ni + r) mx = fmaxf(mx, sa[ni][r]);
      mx = fmaxf(mx, __shfl_xor(mx, 16));
      mx = fmaxf(mx, __shfl_xor(mx, 32));
      float mu = fmaxf(mrun, mx);
      corr = exp2f(mrun - mu);
      float rs = 0.f;
      #pragma unroll
      for (int ni = 0; ni < 4; ++ni)
        #pragma unroll
        for (int r = 0; r < 4; ++r) {
          float pe = exp2f(sa[ni][r] - mu);
          sa[ni][r] = pe;
          rs += pe;
        }
      rs += __shfl_xor(rs, 16);
      rs += __shfl_xor(rs, 32);
      lrun = lrun * corr + rs;
      mrun = mu;
    }

    // build PV B-fragments in-register: pf[c] = P[q=li][kv = c*32 + g*8 + j]
    bf16x8 pf[2];
    #pragma unroll
    for (int c = 0; c < 2; ++c) {
      u32 PA0 = pkbf(sa[2*c  ][0], sa[2*c  ][1]);
      u32 PA1 = pkbf(sa[2*c  ][2], sa[2*c  ][3]);
      u32 PB0 = pkbf(sa[2*c+1][0], sa[2*c+1][1]);
      u32 PB1 = pkbf(sa[2*c+1][2], sa[2*c+1][3]);
      u32 X16_0 = (u32)__shfl_xor((int)((g==2) ? PB0 : PA0), 16);
      u32 X16_1 = (u32)__shfl_xor((int)((g==2) ? PB1 : PA1), 16);
      u32 X32_0 = (u32)__shfl_xor((int)((g==0) ? PB0 : PA0), 32);
      u32 X32_1 = (u32)__shfl_xor((int)((g==0) ? PB1 : PA1), 32);
      u32 X48_0 = (u32)__shfl_xor((int)((g==1) ? PB0 : PA0), 48);
      u32 X48_1 = (u32)__shfl_xor((int)((g==1) ? PB1 : PA1), 48);
      union { u32 u[4]; bf16x8 v; } pbu;
      pbu.u[0] = (g==0) ? PA0   : (g==1) ? X48_0 : (g==2) ? X32_0 : X16_0;
      pbu.u[1] = (g==0) ? PA1   : (g==1) ? X48_1 : (g==2) ? X32_1 : X16_1;
      pbu.u[2] = (g==0) ? X16_0 : (g==1) ? X32_0 : (g==2) ? X48_0 : PB0;
      pbu.u[3] = (g==0) ? X16_1 : (g==1) ? X32_1 : (g==2) ? X48_1 : PB1;
      pf[c] = pbu.v;
    }

    // rescale O^T by corr (per-lane, q=li)
    #pragma unroll
    for (int di = 0; di < 4; ++di) {
      oacc[di][0] *= corr; oacc[di][1] *= corr;
      oacc[di][2] *= corr; oacc[di][3] *= corr;
    }

    // PV: O^T[d][q] += Vt[d][kv] * P^T[kv][q]
    #pragma unroll
    for (int c = 0; c < 2; ++c) {
      #pragma unroll
      for (int di = 0; di < 4; ++di) {
        int d = di*16 + li;
        bf16x8 vf = *(const bf16x8*)(&Vts[d*64 + (((c*4+g) ^ (d&7)))*8]);
        oacc[di] = MFMA(vf, pf[c], oacc[di]);
      }
    }
  }

  // epilogue: per-lane 1/l (q=li), transpose via LDS scratch, coalesced store
  __syncthreads();                          // all waves done with Ks
  unsigned short* scr = &Ks[w*1024];
  float rl = (lrun > 0.f) ? 1.0f / lrun : 0.f;
  #pragma unroll
  for (int di = 0; di < 4; ++di)
    #pragma unroll
    for (int r = 0; r < 4; ++r) {
      int d = di*16 + g*4 + r;
      scr[li*64 + (((d>>3) ^ (li&7)))*8 + (d&7)] = f2b(oacc[di][r] * rl);
    }
  const int D = H * 64;
  #pragma unroll
  for (int rr = 0; rr < 2; ++rr) {
    int q = rr*8 + (lane >> 3);
    int sl = lane & 7;
    bf16x8 v = *(const bf16x8*)(&scr[q*64 + ((sl ^ (q & 7)))*8]);
    *(bf16x8*)(Ob + (size_t)(b*S + q0 + w*16 + q)*D + h*64 + sl*8) = v;
  }
}

extern "C" void kernel_launch(void* const* d_in, const int* in_sizes, int n_in,
                              void* d_out, int out_size, void* d_ws, size_t ws_size,
                              hipStream_t stream) {
  const float* query = (const float*)d_in[0];
  const float* key_  = (const float*)d_in[1];
  const float* value = (const float*)d_in[2];
  const unsigned char* amask = (const unsigned char*)d_in[3];
  const float* Wq   = (const float*)d_in[4];
  const float* Wk   = (const float*)d_in[5];
  const float* Wv   = (const float*)d_in[6];
  const float* Wout = (const float*)d_in[7];
  const float* b_out = (const float*)d_in[8];
  const int* is_causal = (const int*)d_in[9];
  float* out = (float*)d_out;

  const int B = 2, S = 2048, D = 1024, H = 16;
  const int M = B * S;
  const size_t nx = (size_t)M * D;
  const size_t nw = (size_t)D * D;
  const int nU = B * S * (S / 64);

  unsigned short* ws = (unsigned short*)d_ws;
  unsigned short* xq = ws;
  unsigned short* xk = xq + nx;
  unsigned short* xv = xk + nx;
  unsigned short* wq = xv + nx;
  unsigned short* wk = wq + nw;
  unsigned short* wv = wk + nw;
  unsigned short* wo = wv + nw;
  unsigned short* qb = wo + nw;        // [b][h][s][64]
  unsigned short* kb = qb + nx;        // [b][h][s][64]
  unsigned short* vt = kb + nx;        // [b][h][64][s]
  u32* msum = (u32*)(vt + nx);         // [B*S]
  unsigned short* ob = xq;             // reuse: xq dead after Q-projection
  u64* pmask = (u64*)xv;               // reuse: xv dead after V-projection

  cvt7<<<dim3((unsigned)(nx/4/256), 7), 256, 0, stream>>>(
      query, key_, value, Wq, Wk, Wv, Wout,
      xq, xk, xv, wq, wk, wv, wo, (int)(nx/4), (int)(nw/4));

  gemm64<1><<<dim3(M/64, D/128), 256, 0, stream>>>(xq, wq, qb, nullptr, nullptr, M, D, D);
  gemm64<1><<<dim3(M/64, D/128), 256, 0, stream>>>(xk, wk, kb, nullptr, nullptr, M, D, D);
  gemm64<2><<<dim3(D/64, M/128), 256, 0, stream>>>(wv, xv, vt, nullptr, nullptr, D, M, D);

  pack_mask<<<512, 256, 0, stream>>>(amask, pmask, nU);
  mask_summary<<<128, 256, 0, stream>>>(pmask, msum, M, S/64);

  attn_kernel<<<dim3((S/64) * B * H), 256, 0, stream>>>(qb, kb, vt, pmask, msum, is_causal, ob, B, H, S);

  gemm64<0><<<dim3(M/64, D/128), 256, 0, stream>>>(ob, wo, nullptr, out, b_out, M, D, D);
}

// Round 10
// 186.482 us; speedup vs baseline: 1.6995x; 1.0196x over previous
//
#include <hip/hip_runtime.h>
#include <hip/hip_bf16.h>

typedef __attribute__((ext_vector_type(8))) short bf16x8;
typedef __attribute__((ext_vector_type(4))) float f32x4;
typedef unsigned long long u64;
typedef unsigned int u32;

#define MFMA(a,b,c) __builtin_amdgcn_mfma_f32_16x16x32_bf16(a,b,c,0,0,0)
#define NEG_INF (-__builtin_inff())
#define SCALE2 0.1803368801111244f   // 0.125 * log2(e)

__device__ __forceinline__ unsigned short f2b(float f) {
  unsigned int u = __float_as_uint(f);
  u = u + 0x7fffu + ((u >> 16) & 1u);
  return (unsigned short)(u >> 16);
}

__device__ __forceinline__ u32 pkbf(float lo, float hi) {
  __hip_bfloat162 h = __float22bfloat162_rn(float2{lo, hi});
  return *reinterpret_cast<u32*>(&h);
}

__device__ __forceinline__ void gload_lds16(const unsigned short* g, unsigned short* l) {
  __builtin_amdgcn_global_load_lds((const __attribute__((address_space(1))) void*)g,
                                   (__attribute__((address_space(3))) void*)l, 16, 0, 0);
}

// ---------------- fused fp32 -> bf16 conversion for all 7 tensors ----------------
__global__ void cvt7(const float* s0, const float* s1, const float* s2,
                     const float* s3, const float* s4, const float* s5, const float* s6,
                     unsigned short* d0, unsigned short* d1, unsigned short* d2,
                     unsigned short* d3, unsigned short* d4, unsigned short* d5, unsigned short* d6,
                     int nbig, int nsmall) {
  const float* s; unsigned short* d; int n4;
  switch (blockIdx.y) {
    case 0: s=s0; d=d0; n4=nbig; break;
    case 1: s=s1; d=d1; n4=nbig; break;
    case 2: s=s2; d=d2; n4=nbig; break;
    case 3: s=s3; d=d3; n4=nsmall; break;
    case 4: s=s4; d=d4; n4=nsmall; break;
    case 5: s=s5; d=d5; n4=nsmall; break;
    default: s=s6; d=d6; n4=nsmall; break;
  }
  int i = blockIdx.x * blockDim.x + threadIdx.x;
  if (i < n4) {
    float4 v = reinterpret_cast<const float4*>(s)[i];
    ushort4 o;
    o.x = f2b(v.x); o.y = f2b(v.y); o.z = f2b(v.z); o.w = f2b(v.w);
    reinterpret_cast<ushort4*>(d)[i] = o;
  }
}

// ---------------- pack bool mask into bits ----------------
__global__ void pack_mask(const unsigned char* __restrict__ am, u64* __restrict__ pm, int nU) {
  int lane = threadIdx.x & 63;
  int wid = blockIdx.x * (blockDim.x >> 6) + (threadIdx.x >> 6);
  int stride = gridDim.x * (blockDim.x >> 6);
  for (int u = wid; u < nU; u += stride) {
    unsigned char v = am[(size_t)u * 64 + lane];
    u64 m = __ballot(v != 0);
    if (lane == 0) pm[u] = m;
  }
}

// ---------------- per-row tile summary ----------------
__global__ void mask_summary(const u64* __restrict__ pm, u32* __restrict__ ms, int rows, int nkt) {
  int lane = threadIdx.x & 63;
  int wid = (blockIdx.x * blockDim.x + threadIdx.x) >> 6;
  int nw = (gridDim.x * blockDim.x) >> 6;
  for (int rp = wid; rp < (rows >> 1); rp += nw) {
    int row = rp * 2 + (lane >> 5);
    int t = lane & 31;
    u64 v = pm[(size_t)row * nkt + t];
    u64 bm = __ballot(v != 0ULL);
    if (lane == 0)  ms[rp*2]     = (u32)bm;
    if (lane == 32) ms[rp*2 + 1] = (u32)(bm >> 32);
  }
}

// ---------------- merged QKV projection: C = [xq;xk;xv] @ blockdiag(wq,wk,wv)^T ----------------
// A = 12288x1024 (xq|xk|xv contiguous), Bw = 3072x1024 (wq|wk|wv contiguous).
// Block row-third selects B row offset by INDEX (no pointer select).
// Rows < 8192 (Q,K) -> heads layout into Cqk (qb|kb contiguous, (row>>11) = b index 0..3).
// Rows >= 8192 (V)  -> Vt layout [b][h][dk][s] into Cv.  64x128 tile, 4 waves.
__global__ __launch_bounds__(256) void qkv64(
    const unsigned short* __restrict__ A,
    const unsigned short* __restrict__ Bw,
    unsigned short* __restrict__ Cqk,
    unsigned short* __restrict__ Cv)
{
  const int K = 1024;
  __shared__ unsigned short As[64*32];
  __shared__ unsigned short Bs[128*32];
  const int tid  = threadIdx.x;
  const int w    = tid >> 6, lane = tid & 63;
  const int wr   = w >> 1,   wc   = w & 1;
  const int g    = lane >> 4, li  = lane & 15;
  const int m0   = blockIdx.x * 64, n0 = blockIdx.y * 128;
  const int bq0  = (m0 >> 12) * 1024 + n0;   // B row base for this third

  f32x4 acc[2][4] = {};
  const int crow = lane >> 2, ccol = (lane & 3) * 8;
  const unsigned short* gA  = A  + (size_t)(m0 + w*16 + crow)*K + ccol;
  const unsigned short* gB0 = Bw + (size_t)(bq0 + w*16 + crow)*K + ccol;
  const unsigned short* gB1 = Bw + (size_t)(bq0 + (w+4)*16 + crow)*K + ccol;

  for (int k0 = 0; k0 < K; k0 += 32) {
    gload_lds16(gA  + k0, &As[w*512]);
    gload_lds16(gB0 + k0, &Bs[w*512]);
    gload_lds16(gB1 + k0, &Bs[(w+4)*512]);
    __syncthreads();

    bf16x8 af[2], bf[4];
    #pragma unroll
    for (int i = 0; i < 2; ++i)
      af[i] = *(const bf16x8*)(&As[(wr*32 + i*16 + li)*32 + g*8]);
    #pragma unroll
    for (int j = 0; j < 4; ++j)
      bf[j] = *(const bf16x8*)(&Bs[(wc*64 + j*16 + li)*32 + g*8]);
    #pragma unroll
    for (int i = 0; i < 2; ++i)
      #pragma unroll
      for (int j = 0; j < 4; ++j)
        acc[i][j] = MFMA(af[i], bf[j], acc[i][j]);
    __syncthreads();
  }

  #pragma unroll
  for (int i = 0; i < 2; ++i) {
    #pragma unroll
    for (int j = 0; j < 4; ++j) {
      int col = n0 + wc*64 + j*16 + li;
      #pragma unroll
      for (int r = 0; r < 4; ++r) {
        int row = m0 + wr*32 + i*16 + g*4 + r;   // 0..12287
        float v = acc[i][j][r];
        if (row < 8192) {
          // Q,K heads layout: (row>>11) spans b=0..3 over qb|kb contiguous
          size_t addr = (((size_t)(row >> 11) * 16 + (col >> 6)) * 2048 + (row & 2047)) * 64 + (col & 63);
          Cqk[addr] = f2b(v);
        } else {
          // V -> Vt layout [b][h][dk][s]: token t = row&4095, d = col
          int t = row & 4095;
          size_t addr = (((size_t)(t >> 11) * 16 + (col >> 6)) * 64 + (col & 63)) * 2048 + (t & 2047);
          Cv[addr] = f2b(v);
        }
      }
    }
  }
}

// ---------------- GEMM 64x128 tile (final projection, f32 out + bias) ----------------
__global__ __launch_bounds__(256) void gemm64f(
    const unsigned short* __restrict__ A,
    const unsigned short* __restrict__ Bw,
    float* __restrict__ Cf,
    const float* __restrict__ bias,
    int M, int N, int K)
{
  __shared__ unsigned short As[64*32];
  __shared__ unsigned short Bs[128*32];
  const int tid  = threadIdx.x;
  const int w    = tid >> 6, lane = tid & 63;
  const int wr   = w >> 1,   wc   = w & 1;
  const int g    = lane >> 4, li  = lane & 15;
  const int m0   = blockIdx.x * 64, n0 = blockIdx.y * 128;

  f32x4 acc[2][4] = {};
  const int crow = lane >> 2, ccol = (lane & 3) * 8;
  const unsigned short* gA  = A  + (size_t)(m0 + w*16 + crow)*K + ccol;
  const unsigned short* gB0 = Bw + (size_t)(n0 + w*16 + crow)*K + ccol;
  const unsigned short* gB1 = Bw + (size_t)(n0 + (w+4)*16 + crow)*K + ccol;

  for (int k0 = 0; k0 < K; k0 += 32) {
    gload_lds16(gA  + k0, &As[w*512]);
    gload_lds16(gB0 + k0, &Bs[w*512]);
    gload_lds16(gB1 + k0, &Bs[(w+4)*512]);
    __syncthreads();

    bf16x8 af[2], bf[4];
    #pragma unroll
    for (int i = 0; i < 2; ++i)
      af[i] = *(const bf16x8*)(&As[(wr*32 + i*16 + li)*32 + g*8]);
    #pragma unroll
    for (int j = 0; j < 4; ++j)
      bf[j] = *(const bf16x8*)(&Bs[(wc*64 + j*16 + li)*32 + g*8]);
    #pragma unroll
    for (int i = 0; i < 2; ++i)
      #pragma unroll
      for (int j = 0; j < 4; ++j)
        acc[i][j] = MFMA(af[i], bf[j], acc[i][j]);
    __syncthreads();
  }

  #pragma unroll
  for (int i = 0; i < 2; ++i) {
    #pragma unroll
    for (int j = 0; j < 4; ++j) {
      int col = n0 + wc*64 + j*16 + li;
      #pragma unroll
      for (int r = 0; r < 4; ++r) {
        int row = m0 + wr*32 + i*16 + g*4 + r;
        Cf[(size_t)row*N + col] = acc[i][j][r] + bias[col];
      }
    }
  }
}

// ---------------- Flash attention (round-8 green, verbatim) ----------------
__global__ __launch_bounds__(256, 4) void attn_kernel(
    const unsigned short* __restrict__ Qh,   // [B*H][S][64]
    const unsigned short* __restrict__ Kh,   // [B*H][S][64]
    const unsigned short* __restrict__ Vt,   // [B*H][64][S]
    const u64* __restrict__ pmask,           // [B*S][S/64]
    const u32* __restrict__ msum,            // [B*S] tile summary
    const int* __restrict__ causal_p,
    unsigned short* __restrict__ Ob,         // [B*S][H*64]
    int B, int H, int S)
{
  __shared__ unsigned short Ks [64*64];
  __shared__ unsigned short Vts[64*64];

  const int tid = threadIdx.x, w = tid >> 6, lane = tid & 63;
  const int g = lane >> 4, li = lane & 15;
  const int nkt = S >> 6, nqt = S >> 6;
  const int causal = causal_p[0];

  // balanced remap: par/qh mix id bits 0 and 8..9 so any contiguous-4 or
  // stride-256 co-resident set has near-constant total work (66 / 58..74).
  int id = blockIdx.x;
  int par = (id ^ (id >> 8)) & 1;
  int qh  = ((id >> 1) & 15) ^ (((id >> 8) & 3) << 2);
  int bh  = id >> 5;
  int qt  = par ? (nqt - 1 - qh) : qh;
  const int q0 = qt << 6;
  const int b = bh / H, h = bh % H;
  const size_t baseK = (size_t)bh * S * 64;
  const size_t baseV = (size_t)bh * 64 * S;

  // Q fragments (B-operand: lane li = q row, k-cols g*8 / 32+g*8)
  const int qg = q0 + w*16 + li;           // this lane's q row
  const unsigned short* qp = Qh + baseK + (size_t)qg*64 + g*8;
  const bf16x8 qf0 = *(const bf16x8*)(qp);
  const bf16x8 qf1 = *(const bf16x8*)(qp + 32);

  const u32 sOr = msum[(size_t)b*S + qg];

  f32x4 oacc[4] = {};                      // O^T[d][q]: d = di*16+g*4+r, q = li
  float mrun = -1e30f, lrun = 0.f;

  const int colk  = (lane & 7) ^ ((lane >> 3) & 7);
  const int ldrow = lane >> 3;
  const int ntile = causal ? (qt + 1) : nkt;

  for (int t = 0; t < ntile; ++t) {
    const int kv0 = t << 6;
    __syncthreads();
    #pragma unroll
    for (int s2 = 0; s2 < 2; ++s2) {
      int u = w*2 + s2;
      gload_lds16(Kh + baseK + (size_t)(kv0 + u*8 + ldrow)*64 + colk*8, &Ks[u*512]);
      gload_lds16(Vt + baseV + (size_t)(u*8 + ldrow)*S + kv0 + colk*8, &Vts[u*512]);
    }
    __syncthreads();

    // S^T = K * Q^T : sa[ni][r] = S[q=li][kv = kv0 + ni*16 + g*4 + r]
    f32x4 sa[4];
    #pragma unroll
    for (int ni = 0; ni < 4; ++ni) sa[ni] = (f32x4){0.f, 0.f, 0.f, 0.f};
    #pragma unroll
    for (int ni = 0; ni < 4; ++ni) {
      int row = ni*16 + li, rx = row & 7;
      bf16x8 k0 = *(const bf16x8*)(&Ks[row*64 + ((g     ^ rx))*8]);
      bf16x8 k1 = *(const bf16x8*)(&Ks[row*64 + (((4+g) ^ rx))*8]);
      sa[ni] = MFMA(k0, qf0, sa[ni]);
      sa[ni] = MFMA(k1, qf1, sa[ni]);
    }

    const bool edge   = (causal != 0) && (t == ntile - 1);
    const bool doMask = __any(((sOr >> t) & 1u) != 0u);
    float corr;

    if (!edge && !doMask) {
      float mx = sa[0][0];
      #pragma unroll
      for (int ni = 0; ni < 4; ++ni)
        #pragma unroll
        for (int r = 0; r < 4; ++r)
          if (ni + r) mx = fmaxf(mx, sa[ni][r]);
      mx = fmaxf(mx, __shfl_xor(mx, 16));
      mx = fmaxf(mx, __shfl_xor(mx, 32));
      float mu = fmaxf(mrun, mx * SCALE2);
      corr = exp2f(mrun - mu);
      float rs = 0.f;
      #pragma unroll
      for (int ni = 0; ni < 4; ++ni)
        #pragma unroll
        for (int r = 0; r < 4; ++r) {
          float pe = exp2f(fmaf(sa[ni][r], SCALE2, -mu));
          sa[ni][r] = pe;
          rs += pe;
        }
      rs += __shfl_xor(rs, 16);
      rs += __shfl_xor(rs, 32);
      lrun = lrun * corr + rs;
      mrun = mu;
    } else {
      u64 mrow = doMask ? pmask[((size_t)b*S + qg) * nkt + t] : 0ULL;
      #pragma unroll
      for (int ni = 0; ni < 4; ++ni)
        #pragma unroll
        for (int r = 0; r < 4; ++r) {
          int kvloc = ni*16 + g*4 + r;
          bool dead = (edge && (kv0 + kvloc > qg)) || ((mrow >> kvloc) & 1ULL);
          sa[ni][r] = dead ? NEG_INF : sa[ni][r] * SCALE2;
        }
      float mx = sa[0][0];
      #pragma unroll
      for (int ni = 0; ni < 4; ++ni)
        #pragma unroll
        for (int r = 0; r < 4; ++r)
          if (ni + r) mx = fmaxf(mx, sa[ni][r]);
      mx = fmaxf(mx, __shfl_xor(mx, 16));
      mx = fmaxf(mx, __shfl_xor(mx, 32));
      float mu = fmaxf(mrun, mx);
      corr = exp2f(mrun - mu);
      float rs = 0.f;
      #pragma unroll
      for (int ni = 0; ni < 4; ++ni)
        #pragma unroll
        for (int r = 0; r < 4; ++r) {
          float pe = exp2f(sa[ni][r] - mu);
          sa[ni][r] = pe;
          rs += pe;
        }
      rs += __shfl_xor(rs, 16);
      rs += __shfl_xor(rs, 32);
      lrun = lrun * corr + rs;
      mrun = mu;
    }

    // build PV B-fragments in-register: pf[c] = P[q=li][kv = c*32 + g*8 + j]
    bf16x8 pf[2];
    #pragma unroll
    for (int c = 0; c < 2; ++c) {
      u32 PA0 = pkbf(sa[2*c  ][0], sa[2*c  ][1]);
      u32 PA1 = pkbf(sa[2*c  ][2], sa[2*c  ][3]);
      u32 PB0 = pkbf(sa[2*c+1][0], sa[2*c+1][1]);
      u32 PB1 = pkbf(sa[2*c+1][2], sa[2*c+1][3]);
      u32 X16_0 = (u32)__shfl_xor((int)((g==2) ? PB0 : PA0), 16);
      u32 X16_1 = (u32)__shfl_xor((int)((g==2) ? PB1 : PA1), 16);
      u32 X32_0 = (u32)__shfl_xor((int)((g==0) ? PB0 : PA0), 32);
      u32 X32_1 = (u32)__shfl_xor((int)((g==0) ? PB1 : PA1), 32);
      u32 X48_0 = (u32)__shfl_xor((int)((g==1) ? PB0 : PA0), 48);
      u32 X48_1 = (u32)__shfl_xor((int)((g==1) ? PB1 : PA1), 48);
      union { u32 u[4]; bf16x8 v; } pbu;
      pbu.u[0] = (g==0) ? PA0   : (g==1) ? X48_0 : (g==2) ? X32_0 : X16_0;
      pbu.u[1] = (g==0) ? PA1   : (g==1) ? X48_1 : (g==2) ? X32_1 : X16_1;
      pbu.u[2] = (g==0) ? X16_0 : (g==1) ? X32_0 : (g==2) ? X48_0 : PB0;
      pbu.u[3] = (g==0) ? X16_1 : (g==1) ? X32_1 : (g==2) ? X48_1 : PB1;
      pf[c] = pbu.v;
    }

    // rescale O^T by corr (per-lane, q=li)
    #pragma unroll
    for (int di = 0; di < 4; ++di) {
      oacc[di][0] *= corr; oacc[di][1] *= corr;
      oacc[di][2] *= corr; oacc[di][3] *= corr;
    }

    // PV: O^T[d][q] += Vt[d][kv] * P^T[kv][q]
    #pragma unroll
    for (int c = 0; c < 2; ++c) {
      #pragma unroll
      for (int di = 0; di < 4; ++di) {
        int d = di*16 + li;
        bf16x8 vf = *(const bf16x8*)(&Vts[d*64 + (((c*4+g) ^ (d&7)))*8]);
        oacc[di] = MFMA(vf, pf[c], oacc[di]);
      }
    }
  }

  // epilogue: per-lane 1/l (q=li), transpose via LDS scratch, coalesced store
  __syncthreads();                          // all waves done with Ks
  unsigned short* scr = &Ks[w*1024];
  float rl = (lrun > 0.f) ? 1.0f / lrun : 0.f;
  #pragma unroll
  for (int di = 0; di < 4; ++di)
    #pragma unroll
    for (int r = 0; r < 4; ++r) {
      int d = di*16 + g*4 + r;
      scr[li*64 + (((d>>3) ^ (li&7)))*8 + (d&7)] = f2b(oacc[di][r] * rl);
    }
  const int D = H * 64;
  #pragma unroll
  for (int rr = 0; rr < 2; ++rr) {
    int q = rr*8 + (lane >> 3);
    int sl = lane & 7;
    bf16x8 v = *(const bf16x8*)(&scr[q*64 + ((sl ^ (q & 7)))*8]);
    *(bf16x8*)(Ob + (size_t)(b*S + q0 + w*16 + q)*D + h*64 + sl*8) = v;
  }
}

extern "C" void kernel_launch(void* const* d_in, const int* in_sizes, int n_in,
                              void* d_out, int out_size, void* d_ws, size_t ws_size,
                              hipStream_t stream) {
  const float* query = (const float*)d_in[0];
  const float* key_  = (const float*)d_in[1];
  const float* value = (const float*)d_in[2];
  const unsigned char* amask = (const unsigned char*)d_in[3];
  const float* Wq   = (const float*)d_in[4];
  const float* Wk   = (const float*)d_in[5];
  const float* Wv   = (const float*)d_in[6];
  const float* Wout = (const float*)d_in[7];
  const float* b_out = (const float*)d_in[8];
  const int* is_causal = (const int*)d_in[9];
  float* out = (float*)d_out;

  const int B = 2, S = 2048, D = 1024, H = 16;
  const int M = B * S;
  const size_t nx = (size_t)M * D;
  const size_t nw = (size_t)D * D;
  const int nU = B * S * (S / 64);

  unsigned short* ws = (unsigned short*)d_ws;
  unsigned short* xq = ws;                 // A = xq|xk|xv contiguous (12288x1024)
  unsigned short* xk = xq + nx;
  unsigned short* xv = xk + nx;
  unsigned short* wq = xv + nx;            // Bw = wq|wk|wv contiguous (3072x1024)
  unsigned short* wk = wq + nw;
  unsigned short* wv = wk + nw;
  unsigned short* wo = wv + nw;
  unsigned short* qb = wo + nw;            // [b][h][s][64]; kb contiguous after
  unsigned short* kb = qb + nx;            // [b][h][s][64]
  unsigned short* vt = kb + nx;            // [b][h][64][s]
  u32* msum = (u32*)(vt + nx);             // [B*S]
  unsigned short* ob = xq;                 // reuse: xq dead after QKV projection
  u64* pmask = (u64*)xv;                   // reuse: xv dead after QKV projection

  cvt7<<<dim3((unsigned)(nx/4/256), 7), 256, 0, stream>>>(
      query, key_, value, Wq, Wk, Wv, Wout,
      xq, xk, xv, wq, wk, wv, wo, (int)(nx/4), (int)(nw/4));

  qkv64<<<dim3(3*M/64, D/128), 256, 0, stream>>>(xq, wq, qb, vt);

  pack_mask<<<512, 256, 0, stream>>>(amask, pmask, nU);
  mask_summary<<<128, 256, 0, stream>>>(pmask, msum, M, S/64);

  attn_kernel<<<dim3((S/64) * B * H), 256, 0, stream>>>(qb, kb, vt, pmask, msum, is_causal, ob, B, H, S);

  gemm64f<<<dim3(M/64, D/128), 256, 0, stream>>>(ob, wo, out, b_out, M, D, D);
}

// Round 11
// 172.905 us; speedup vs baseline: 1.8329x; 1.0785x over previous
//
#include <hip/hip_runtime.h>
#include <hip/hip_bf16.h>

typedef __attribute__((ext_vector_type(8))) short bf16x8;
typedef __attribute__((ext_vector_type(4))) float f32x4;
typedef unsigned long long u64;
typedef unsigned int u32;

#define MFMA(a,b,c) __builtin_amdgcn_mfma_f32_16x16x32_bf16(a,b,c,0,0,0)
#define NEG_INF (-__builtin_inff())
#define SCALE2 0.1803368801111244f   // 0.125 * log2(e)

__device__ __forceinline__ unsigned short f2b(float f) {
  unsigned int u = __float_as_uint(f);
  u = u + 0x7fffu + ((u >> 16) & 1u);
  return (unsigned short)(u >> 16);
}

__device__ __forceinline__ u32 pkbf(float lo, float hi) {
  __hip_bfloat162 h = __float22bfloat162_rn(float2{lo, hi});
  return *reinterpret_cast<u32*>(&h);
}

__device__ __forceinline__ void gload_lds16(const unsigned short* g, unsigned short* l) {
  __builtin_amdgcn_global_load_lds((const __attribute__((address_space(1))) void*)g,
                                   (__attribute__((address_space(3))) void*)l, 16, 0, 0);
}

// ---------------- fused fp32 -> bf16 conversion for all 7 tensors ----------------
__global__ void cvt7(const float* s0, const float* s1, const float* s2,
                     const float* s3, const float* s4, const float* s5, const float* s6,
                     unsigned short* d0, unsigned short* d1, unsigned short* d2,
                     unsigned short* d3, unsigned short* d4, unsigned short* d5, unsigned short* d6,
                     int nbig, int nsmall) {
  const float* s; unsigned short* d; int n4;
  switch (blockIdx.y) {
    case 0: s=s0; d=d0; n4=nbig; break;
    case 1: s=s1; d=d1; n4=nbig; break;
    case 2: s=s2; d=d2; n4=nbig; break;
    case 3: s=s3; d=d3; n4=nsmall; break;
    case 4: s=s4; d=d4; n4=nsmall; break;
    case 5: s=s5; d=d5; n4=nsmall; break;
    default: s=s6; d=d6; n4=nsmall; break;
  }
  int i = blockIdx.x * blockDim.x + threadIdx.x;
  if (i < n4) {
    float4 v = reinterpret_cast<const float4*>(s)[i];
    ushort4 o;
    o.x = f2b(v.x); o.y = f2b(v.y); o.z = f2b(v.z); o.w = f2b(v.w);
    reinterpret_cast<ushort4*>(d)[i] = o;
  }
}

// ---------------- pack bool mask into bits ----------------
__global__ void pack_mask(const unsigned char* __restrict__ am, u64* __restrict__ pm, int nU) {
  int lane = threadIdx.x & 63;
  int wid = blockIdx.x * (blockDim.x >> 6) + (threadIdx.x >> 6);
  int stride = gridDim.x * (blockDim.x >> 6);
  for (int u = wid; u < nU; u += stride) {
    unsigned char v = am[(size_t)u * 64 + lane];
    u64 m = __ballot(v != 0);
    if (lane == 0) pm[u] = m;
  }
}

// ---------------- per-row tile summary ----------------
__global__ void mask_summary(const u64* __restrict__ pm, u32* __restrict__ ms, int rows, int nkt) {
  int lane = threadIdx.x & 63;
  int wid = (blockIdx.x * blockDim.x + threadIdx.x) >> 6;
  int nw = (gridDim.x * blockDim.x) >> 6;
  for (int rp = wid; rp < (rows >> 1); rp += nw) {
    int row = rp * 2 + (lane >> 5);
    int t = lane & 31;
    u64 v = pm[(size_t)row * nkt + t];
    u64 bm = __ballot(v != 0ULL);
    if (lane == 0)  ms[rp*2]     = (u32)bm;
    if (lane == 32) ms[rp*2 + 1] = (u32)(bm >> 32);
  }
}

// ---------------- merged QKV projection, 128x128 tile, 2-phase dbuf ----------------
// A = 12288x1024 (xq|xk|xv), Bw = 3072x1024 (wq|wk|wv); B row base by INDEX.
// Rows < 8192 (Q,K) -> heads layout into Cqk; rows >= 8192 (V) -> Vt into Cv.
__global__ __launch_bounds__(256) void qkv128(
    const unsigned short* __restrict__ A,
    const unsigned short* __restrict__ Bw,
    unsigned short* __restrict__ Cqk,
    unsigned short* __restrict__ Cv)
{
  const int K = 1024, NT = 32;
  __shared__ unsigned short As[2][128*32];
  __shared__ unsigned short Bs[2][128*32];
  const int tid  = threadIdx.x;
  const int w    = tid >> 6, lane = tid & 63;
  const int wr   = w >> 1,   wc   = w & 1;
  const int g    = lane >> 4, li  = lane & 15;
  const int m0   = blockIdx.x * 128, n0 = blockIdx.y * 128;
  const int bq0  = (m0 >> 12) * 1024 + n0;   // B row base for this third

  f32x4 acc[4][4] = {};

  const int rS0 = (w*2+0)*16 + (lane>>2);
  const int rS1 = (w*2+1)*16 + (lane>>2);
  const int cS  = (lane&3)*8;
  const unsigned short* gA0 = A  + (size_t)(m0+rS0)*K + cS;
  const unsigned short* gA1 = A  + (size_t)(m0+rS1)*K + cS;
  const unsigned short* gB0 = Bw + (size_t)(bq0+rS0)*K + cS;
  const unsigned short* gB1 = Bw + (size_t)(bq0+rS1)*K + cS;

  // prologue: stage tile 0 into buffer 0
  gload_lds16(gA0, &As[0][(w*2+0)*512]);
  gload_lds16(gA1, &As[0][(w*2+1)*512]);
  gload_lds16(gB0, &Bs[0][(w*2+0)*512]);
  gload_lds16(gB1, &Bs[0][(w*2+1)*512]);
  __syncthreads();

  for (int t = 0; t < NT; ++t) {
    const int cur = t & 1;
    if (t + 1 < NT) {
      const int k1 = (t + 1) * 32;
      gload_lds16(gA0 + k1, &As[cur^1][(w*2+0)*512]);
      gload_lds16(gA1 + k1, &As[cur^1][(w*2+1)*512]);
      gload_lds16(gB0 + k1, &Bs[cur^1][(w*2+0)*512]);
      gload_lds16(gB1 + k1, &Bs[cur^1][(w*2+1)*512]);
    }
    bf16x8 af[4], bf[4];
    #pragma unroll
    for (int i = 0; i < 4; ++i)
      af[i] = *(const bf16x8*)(&As[cur][(wr*64 + i*16 + li)*32 + g*8]);
    #pragma unroll
    for (int j = 0; j < 4; ++j)
      bf[j] = *(const bf16x8*)(&Bs[cur][(wc*64 + j*16 + li)*32 + g*8]);
    #pragma unroll
    for (int i = 0; i < 4; ++i)
      #pragma unroll
      for (int j = 0; j < 4; ++j)
        acc[i][j] = MFMA(af[i], bf[j], acc[i][j]);
    __syncthreads();   // drains prefetch (vmcnt) + LDS reads (lgkm)
  }

  #pragma unroll
  for (int i = 0; i < 4; ++i) {
    #pragma unroll
    for (int j = 0; j < 4; ++j) {
      int col = n0 + wc*64 + j*16 + li;
      #pragma unroll
      for (int r = 0; r < 4; ++r) {
        int row = m0 + wr*64 + i*16 + g*4 + r;   // 0..12287
        float v = acc[i][j][r];
        if (row < 8192) {
          size_t addr = (((size_t)(row >> 11) * 16 + (col >> 6)) * 2048 + (row & 2047)) * 64 + (col & 63);
          Cqk[addr] = f2b(v);
        } else {
          int tk = row & 4095;
          size_t addr = (((size_t)(tk >> 11) * 16 + (col >> 6)) * 64 + (col & 63)) * 2048 + (tk & 2047);
          Cv[addr] = f2b(v);
        }
      }
    }
  }
}

// ---------------- final projection GEMM, 64x128 tile, 2-phase dbuf ----------------
__global__ __launch_bounds__(256) void gemm64db(
    const unsigned short* __restrict__ A,
    const unsigned short* __restrict__ Bw,
    float* __restrict__ Cf,
    const float* __restrict__ bias,
    int M, int N, int K)
{
  const int NT = 32;   // K/32 = 1024/32
  __shared__ unsigned short As[2][64*32];
  __shared__ unsigned short Bs[2][128*32];
  const int tid  = threadIdx.x;
  const int w    = tid >> 6, lane = tid & 63;
  const int wr   = w >> 1,   wc   = w & 1;
  const int g    = lane >> 4, li  = lane & 15;
  const int m0   = blockIdx.x * 64, n0 = blockIdx.y * 128;

  f32x4 acc[2][4] = {};
  const int crow = lane >> 2, ccol = (lane & 3) * 8;
  const unsigned short* gA  = A  + (size_t)(m0 + w*16 + crow)*K + ccol;
  const unsigned short* gB0 = Bw + (size_t)(n0 + w*16 + crow)*K + ccol;
  const unsigned short* gB1 = Bw + (size_t)(n0 + (w+4)*16 + crow)*K + ccol;

  // prologue
  gload_lds16(gA,  &As[0][w*512]);
  gload_lds16(gB0, &Bs[0][w*512]);
  gload_lds16(gB1, &Bs[0][(w+4)*512]);
  __syncthreads();

  for (int t = 0; t < NT; ++t) {
    const int cur = t & 1;
    if (t + 1 < NT) {
      const int k1 = (t + 1) * 32;
      gload_lds16(gA  + k1, &As[cur^1][w*512]);
      gload_lds16(gB0 + k1, &Bs[cur^1][w*512]);
      gload_lds16(gB1 + k1, &Bs[cur^1][(w+4)*512]);
    }
    bf16x8 af[2], bf[4];
    #pragma unroll
    for (int i = 0; i < 2; ++i)
      af[i] = *(const bf16x8*)(&As[cur][(wr*32 + i*16 + li)*32 + g*8]);
    #pragma unroll
    for (int j = 0; j < 4; ++j)
      bf[j] = *(const bf16x8*)(&Bs[cur][(wc*64 + j*16 + li)*32 + g*8]);
    #pragma unroll
    for (int i = 0; i < 2; ++i)
      #pragma unroll
      for (int j = 0; j < 4; ++j)
        acc[i][j] = MFMA(af[i], bf[j], acc[i][j]);
    __syncthreads();
  }

  #pragma unroll
  for (int i = 0; i < 2; ++i) {
    #pragma unroll
    for (int j = 0; j < 4; ++j) {
      int col = n0 + wc*64 + j*16 + li;
      #pragma unroll
      for (int r = 0; r < 4; ++r) {
        int row = m0 + wr*32 + i*16 + g*4 + r;
        Cf[(size_t)row*N + col] = acc[i][j][r] + bias[col];
      }
    }
  }
}

// ---------------- Flash attention (round-8 green, verbatim) ----------------
__global__ __launch_bounds__(256, 4) void attn_kernel(
    const unsigned short* __restrict__ Qh,   // [B*H][S][64]
    const unsigned short* __restrict__ Kh,   // [B*H][S][64]
    const unsigned short* __restrict__ Vt,   // [B*H][64][S]
    const u64* __restrict__ pmask,           // [B*S][S/64]
    const u32* __restrict__ msum,            // [B*S] tile summary
    const int* __restrict__ causal_p,
    unsigned short* __restrict__ Ob,         // [B*S][H*64]
    int B, int H, int S)
{
  __shared__ unsigned short Ks [64*64];
  __shared__ unsigned short Vts[64*64];

  const int tid = threadIdx.x, w = tid >> 6, lane = tid & 63;
  const int g = lane >> 4, li = lane & 15;
  const int nkt = S >> 6, nqt = S >> 6;
  const int causal = causal_p[0];

  // balanced remap: par/qh mix id bits 0 and 8..9 so any contiguous-4 or
  // stride-256 co-resident set has near-constant total work (66 / 58..74).
  int id = blockIdx.x;
  int par = (id ^ (id >> 8)) & 1;
  int qh  = ((id >> 1) & 15) ^ (((id >> 8) & 3) << 2);
  int bh  = id >> 5;
  int qt  = par ? (nqt - 1 - qh) : qh;
  const int q0 = qt << 6;
  const int b = bh / H, h = bh % H;
  const size_t baseK = (size_t)bh * S * 64;
  const size_t baseV = (size_t)bh * 64 * S;

  // Q fragments (B-operand: lane li = q row, k-cols g*8 / 32+g*8)
  const int qg = q0 + w*16 + li;           // this lane's q row
  const unsigned short* qp = Qh + baseK + (size_t)qg*64 + g*8;
  const bf16x8 qf0 = *(const bf16x8*)(qp);
  const bf16x8 qf1 = *(const bf16x8*)(qp + 32);

  const u32 sOr = msum[(size_t)b*S + qg];

  f32x4 oacc[4] = {};                      // O^T[d][q]: d = di*16+g*4+r, q = li
  float mrun = -1e30f, lrun = 0.f;

  const int colk  = (lane & 7) ^ ((lane >> 3) & 7);
  const int ldrow = lane >> 3;
  const int ntile = causal ? (qt + 1) : nkt;

  for (int t = 0; t < ntile; ++t) {
    const int kv0 = t << 6;
    __syncthreads();
    #pragma unroll
    for (int s2 = 0; s2 < 2; ++s2) {
      int u = w*2 + s2;
      gload_lds16(Kh + baseK + (size_t)(kv0 + u*8 + ldrow)*64 + colk*8, &Ks[u*512]);
      gload_lds16(Vt + baseV + (size_t)(u*8 + ldrow)*S + kv0 + colk*8, &Vts[u*512]);
    }
    __syncthreads();

    // S^T = K * Q^T : sa[ni][r] = S[q=li][kv = kv0 + ni*16 + g*4 + r]
    f32x4 sa[4];
    #pragma unroll
    for (int ni = 0; ni < 4; ++ni) sa[ni] = (f32x4){0.f, 0.f, 0.f, 0.f};
    #pragma unroll
    for (int ni = 0; ni < 4; ++ni) {
      int row = ni*16 + li, rx = row & 7;
      bf16x8 k0 = *(const bf16x8*)(&Ks[row*64 + ((g     ^ rx))*8]);
      bf16x8 k1 = *(const bf16x8*)(&Ks[row*64 + (((4+g) ^ rx))*8]);
      sa[ni] = MFMA(k0, qf0, sa[ni]);
      sa[ni] = MFMA(k1, qf1, sa[ni]);
    }

    const bool edge   = (causal != 0) && (t == ntile - 1);
    const bool doMask = __any(((sOr >> t) & 1u) != 0u);
    float corr;

    if (!edge && !doMask) {
      float mx = sa[0][0];
      #pragma unroll
      for (int ni = 0; ni < 4; ++ni)
        #pragma unroll
        for (int r = 0; r < 4; ++r)
          if (ni + r) mx = fmaxf(mx, sa[ni][r]);
      mx = fmaxf(mx, __shfl_xor(mx, 16));
      mx = fmaxf(mx, __shfl_xor(mx, 32));
      float mu = fmaxf(mrun, mx * SCALE2);
      corr = exp2f(mrun - mu);
      float rs = 0.f;
      #pragma unroll
      for (int ni = 0; ni < 4; ++ni)
        #pragma unroll
        for (int r = 0; r < 4; ++r) {
          float pe = exp2f(fmaf(sa[ni][r], SCALE2, -mu));
          sa[ni][r] = pe;
          rs += pe;
        }
      rs += __shfl_xor(rs, 16);
      rs += __shfl_xor(rs, 32);
      lrun = lrun * corr + rs;
      mrun = mu;
    } else {
      u64 mrow = doMask ? pmask[((size_t)b*S + qg) * nkt + t] : 0ULL;
      #pragma unroll
      for (int ni = 0; ni < 4; ++ni)
        #pragma unroll
        for (int r = 0; r < 4; ++r) {
          int kvloc = ni*16 + g*4 + r;
          bool dead = (edge && (kv0 + kvloc > qg)) || ((mrow >> kvloc) & 1ULL);
          sa[ni][r] = dead ? NEG_INF : sa[ni][r] * SCALE2;
        }
      float mx = sa[0][0];
      #pragma unroll
      for (int ni = 0; ni < 4; ++ni)
        #pragma unroll
        for (int r = 0; r < 4; ++r)
          if (ni + r) mx = fmaxf(mx, sa[ni][r]);
      mx = fmaxf(mx, __shfl_xor(mx, 16));
      mx = fmaxf(mx, __shfl_xor(mx, 32));
      float mu = fmaxf(mrun, mx);
      corr = exp2f(mrun - mu);
      float rs = 0.f;
      #pragma unroll
      for (int ni = 0; ni < 4; ++ni)
        #pragma unroll
        for (int r = 0; r < 4; ++r) {
          float pe = exp2f(sa[ni][r] - mu);
          sa[ni][r] = pe;
          rs += pe;
        }
      rs += __shfl_xor(rs, 16);
      rs += __shfl_xor(rs, 32);
      lrun = lrun * corr + rs;
      mrun = mu;
    }

    // build PV B-fragments in-register: pf[c] = P[q=li][kv = c*32 + g*8 + j]
    bf16x8 pf[2];
    #pragma unroll
    for (int c = 0; c < 2; ++c) {
      u32 PA0 = pkbf(sa[2*c  ][0], sa[2*c  ][1]);
      u32 PA1 = pkbf(sa[2*c  ][2], sa[2*c  ][3]);
      u32 PB0 = pkbf(sa[2*c+1][0], sa[2*c+1][1]);
      u32 PB1 = pkbf(sa[2*c+1][2], sa[2*c+1][3]);
      u32 X16_0 = (u32)__shfl_xor((int)((g==2) ? PB0 : PA0), 16);
      u32 X16_1 = (u32)__shfl_xor((int)((g==2) ? PB1 : PA1), 16);
      u32 X32_0 = (u32)__shfl_xor((int)((g==0) ? PB0 : PA0), 32);
      u32 X32_1 = (u32)__shfl_xor((int)((g==0) ? PB1 : PA1), 32);
      u32 X48_0 = (u32)__shfl_xor((int)((g==1) ? PB0 : PA0), 48);
      u32 X48_1 = (u32)__shfl_xor((int)((g==1) ? PB1 : PA1), 48);
      union { u32 u[4]; bf16x8 v; } pbu;
      pbu.u[0] = (g==0) ? PA0   : (g==1) ? X48_0 : (g==2) ? X32_0 : X16_0;
      pbu.u[1] = (g==0) ? PA1   : (g==1) ? X48_1 : (g==2) ? X32_1 : X16_1;
      pbu.u[2] = (g==0) ? X16_0 : (g==1) ? X32_0 : (g==2) ? X48_0 : PB0;
      pbu.u[3] = (g==0) ? X16_1 : (g==1) ? X32_1 : (g==2) ? X48_1 : PB1;
      pf[c] = pbu.v;
    }

    // rescale O^T by corr (per-lane, q=li)
    #pragma unroll
    for (int di = 0; di < 4; ++di) {
      oacc[di][0] *= corr; oacc[di][1] *= corr;
      oacc[di][2] *= corr; oacc[di][3] *= corr;
    }

    // PV: O^T[d][q] += Vt[d][kv] * P^T[kv][q]
    #pragma unroll
    for (int c = 0; c < 2; ++c) {
      #pragma unroll
      for (int di = 0; di < 4; ++di) {
        int d = di*16 + li;
        bf16x8 vf = *(const bf16x8*)(&Vts[d*64 + (((c*4+g) ^ (d&7)))*8]);
        oacc[di] = MFMA(vf, pf[c], oacc[di]);
      }
    }
  }

  // epilogue: per-lane 1/l (q=li), transpose via LDS scratch, coalesced store
  __syncthreads();                          // all waves done with Ks
  unsigned short* scr = &Ks[w*1024];
  float rl = (lrun > 0.f) ? 1.0f / lrun : 0.f;
  #pragma unroll
  for (int di = 0; di < 4; ++di)
    #pragma unroll
    for (int r = 0; r < 4; ++r) {
      int d = di*16 + g*4 + r;
      scr[li*64 + (((d>>3) ^ (li&7)))*8 + (d&7)] = f2b(oacc[di][r] * rl);
    }
  const int D = H * 64;
  #pragma unroll
  for (int rr = 0; rr < 2; ++rr) {
    int q = rr*8 + (lane >> 3);
    int sl = lane & 7;
    bf16x8 v = *(const bf16x8*)(&scr[q*64 + ((sl ^ (q & 7)))*8]);
    *(bf16x8*)(Ob + (size_t)(b*S + q0 + w*16 + q)*D + h*64 + sl*8) = v;
  }
}

extern "C" void kernel_launch(void* const* d_in, const int* in_sizes, int n_in,
                              void* d_out, int out_size, void* d_ws, size_t ws_size,
                              hipStream_t stream) {
  const float* query = (const float*)d_in[0];
  const float* key_  = (const float*)d_in[1];
  const float* value = (const float*)d_in[2];
  const unsigned char* amask = (const unsigned char*)d_in[3];
  const float* Wq   = (const float*)d_in[4];
  const float* Wk   = (const float*)d_in[5];
  const float* Wv   = (const float*)d_in[6];
  const float* Wout = (const float*)d_in[7];
  const float* b_out = (const float*)d_in[8];
  const int* is_causal = (const int*)d_in[9];
  float* out = (float*)d_out;

  const int B = 2, S = 2048, D = 1024, H = 16;
  const int M = B * S;
  const size_t nx = (size_t)M * D;
  const size_t nw = (size_t)D * D;
  const int nU = B * S * (S / 64);

  unsigned short* ws = (unsigned short*)d_ws;
  unsigned short* xq = ws;                 // A = xq|xk|xv contiguous (12288x1024)
  unsigned short* xk = xq + nx;
  unsigned short* xv = xk + nx;
  unsigned short* wq = xv + nx;            // Bw = wq|wk|wv contiguous (3072x1024)
  unsigned short* wk = wq + nw;
  unsigned short* wv = wk + nw;
  unsigned short* wo = wv + nw;
  unsigned short* qb = wo + nw;            // [b][h][s][64]; kb contiguous after
  unsigned short* kb = qb + nx;            // [b][h][s][64]
  unsigned short* vt = kb + nx;            // [b][h][64][s]
  u32* msum = (u32*)(vt + nx);             // [B*S]
  unsigned short* ob = xq;                 // reuse: xq dead after QKV projection
  u64* pmask = (u64*)xv;                   // reuse: xv dead after QKV projection

  cvt7<<<dim3((unsigned)(nx/4/256), 7), 256, 0, stream>>>(
      query, key_, value, Wq, Wk, Wv, Wout,
      xq, xk, xv, wq, wk, wv, wo, (int)(nx/4), (int)(nw/4));

  qkv128<<<dim3(3*M/128, D/128), 256, 0, stream>>>(xq, wq, qb, vt);

  pack_mask<<<512, 256, 0, stream>>>(amask, pmask, nU);
  mask_summary<<<128, 256, 0, stream>>>(pmask, msum, M, S/64);

  attn_kernel<<<dim3((S/64) * B * H), 256, 0, stream>>>(qb, kb, vt, pmask, msum, is_causal, ob, B, H, S);

  gemm64db<<<dim3(M/64, D/128), 256, 0, stream>>>(ob, wo, out, b_out, M, D, D);
}